// Round 1
// baseline (1297.518 us; speedup 1.0000x reference)
//
#include <hip/hip_runtime.h>
#include <hip/hip_bf16.h>
#include <math.h>

// ---------------------------------------------------------------------------
// sMLP4 round 11: TIME-FUSED layer 1.
//   The h1 pPLIF recurrence is elementwise over (b,o); the only coupling is
//   the GEMM. So fuse the 50-step time loop INSIDE the GEMM: each wave owns
//   one 32x32 output tile, membranes in f64 regs, spikes as a 16-bit mask,
//   and iterates t=0..49 (25 kc x 5 int8-slice MFMAs per step, Horner +
//   membrane update in-register, h1sc byte out). T1 (82 MB write + 82 MB
//   re-read per old chunk), h1m/h1s state arrays, rec1, and chunking are
//   all eliminated. 4 dispatches total: setup -> fused1 -> gemm2 -> rec2.
//   - B1 re-laid-out [nt][kc][s][lane][16]: per-nt slice contiguous; digit
//     slices 0..3 pinned in 100 KB dynamic LDS for the WHOLE kernel (one
//     load, one barrier, then no syncs at all); slice 4 streamed from
//     global (per-XCD L2-resident, 800 KB).
//   - grid 256 = nt*8 + mtg so XCD = id%8 = mtg: each XCD streams only its
//     4-mt slice of A (once), keeps all-nt slice-4 of B resident.
//   - dual-bank accumulators CA/CB: the 16-elem epilogue of step t-1 is
//     interleaved into kc 0..15 of step t's MFMA loop (hides ~800 f64 cyc).
//   Budget: MFMA floor 95us; LDS 16 b128/round ~192cyc vs MFMA 182cyc.
//   Trajectory bit-identical to round 10 (same digits/Horner/f64 order).
// ---------------------------------------------------------------------------

#define NSTEPS 50
#define KC1 25                     // real K chunks for layer 1 (800 >= 784)
#define NSL 5                      // digit slices (digits 1..5 of 2^48 fix-pt)

typedef __attribute__((ext_vector_type(4)))  int i32x4;
typedef __attribute__((ext_vector_type(16))) int i32x16;

// fixed workspace layout (bytes, all 256-aligned)
#define OFF_B1     0ull            // i8 [32*26*5*64*16] = 4,259,840
#define OFF_B2     4259840ull      // i8 [5*4*32*1024]   =   655,360
#define OFF_AF     4915200ull      // i8 [50*32*26*64*16]= 42,598,400
#define OFF_H1SC   47513600ull     // i8 [50*1024*1024]  = 52,428,800
#define OFF_T2     99942400ull     // f64[50*1024*128]   = 52,428,800
#define OFF_H2M    152371200ull    // f64[1024*128]      = 1,048,576
#define OFF_H2S    153419776ull    // i8 [1024*128]      =   131,072
#define OFF_ACC    153550848ull    // f64[1024*10]       =    81,920
#define WS_END     153632768ull    // 146.5 MB (prev rounds used >= 168 MB)

#define PREP_BLOCKS 3840           // (851,968 + 131,072) / 256

// ---------------------------------------------------------------------------
// threefry2x32, key (0,42), partitionable mode: bits(i) = x0^x1 on ctr (0,i)
// ---------------------------------------------------------------------------
__device__ __forceinline__ unsigned int rotl32(unsigned int v, int d) {
#if __has_builtin(__builtin_amdgcn_alignbit)
  return __builtin_amdgcn_alignbit(v, v, (unsigned int)(32 - d));
#else
  return (v << d) | (v >> (32 - d));
#endif
}

__device__ __forceinline__ unsigned int tf_bits(unsigned int i) {
  const unsigned int ks0 = 0u;
  const unsigned int ks1 = 42u;
  const unsigned int ks2 = 0x1BD11BDAu ^ 0u ^ 42u;
  unsigned int x0 = 0u + ks0;
  unsigned int x1 = i + ks1;
#define TF_RND(r) { x0 += x1; x1 = rotl32(x1, r); x1 ^= x0; }
  TF_RND(13) TF_RND(15) TF_RND(26) TF_RND(6)
  x0 += ks1; x1 += ks2 + 1u;
  TF_RND(17) TF_RND(29) TF_RND(16) TF_RND(24)
  x0 += ks2; x1 += ks0 + 2u;
  TF_RND(13) TF_RND(15) TF_RND(26) TF_RND(6)
  x0 += ks0; x1 += ks1 + 3u;
  TF_RND(17) TF_RND(29) TF_RND(16) TF_RND(24)
  x0 += ks1; x1 += ks2 + 4u;
  TF_RND(13) TF_RND(15) TF_RND(26) TF_RND(6)
  x0 += ks2; x1 += ks0 + 5u;
#undef TF_RND
  return x0 ^ x1;
}

// ---------------------------------------------------------------------------
// spikegen role (one block = 4 waves = 4 (t,mt,kc) groups).
// A-frag: lane holds A[m = mt*32+(lane&31)][k = kc*32+(lane>>5)*16+jj].
// Integer compare: u < x  <=>  (bits>>9) < ceil(x*2^23)   (both exact).
// ---------------------------------------------------------------------------
__device__ __forceinline__ void spike_block(
    const float* __restrict__ x, i32x4* __restrict__ A, int t0, int gblk,
    int tid) {
  int g = gblk * 4 + (tid >> 6);
  int lane = tid & 63;
  int kc = g % 25;
  int r = g / 25;                     // tl*32 + mt
  int mt = r & 31;
  int t = t0 + (r >> 5);
  int b = mt * 32 + (lane & 31);
  int j0 = kc * 32 + ((lane >> 5) << 4);
  unsigned int wds[4] = {0u, 0u, 0u, 0u};
  if (j0 < 784) {                     // 784 = 49*16: wave-uniform guard
    unsigned int base = (unsigned int)(t * 1024 + b) * 784u + (unsigned int)j0;
    const float* xp = x + b * 784 + j0;
#pragma unroll
    for (int q = 0; q < 4; ++q) {
      float4 xv = *(const float4*)(xp + 4 * q);
      unsigned int K0 = (unsigned int)(int)ceilf(xv.x * 8388608.0f);
      unsigned int K1 = (unsigned int)(int)ceilf(xv.y * 8388608.0f);
      unsigned int K2 = (unsigned int)(int)ceilf(xv.z * 8388608.0f);
      unsigned int K3 = (unsigned int)(int)ceilf(xv.w * 8388608.0f);
      unsigned int w4 = 0u;
      if ((tf_bits(base + 4 * q + 0) >> 9) < K0) w4 |= 1u;
      if ((tf_bits(base + 4 * q + 1) >> 9) < K1) w4 |= 1u << 8;
      if ((tf_bits(base + 4 * q + 2) >> 9) < K2) w4 |= 1u << 16;
      if ((tf_bits(base + 4 * q + 3) >> 9) < K3) w4 |= 1u << 24;
      wds[q] = w4;
    }
  }
  i32x4 v;
  v.x = (int)wds[0]; v.y = (int)wds[1]; v.z = (int)wds[2]; v.w = (int)wds[3];
  A[(size_t)(((t * 32 + mt) * 26) + kc) * 64 + lane] = v;
}

// ---------------------------------------------------------------------------
// setup: one thread per WEIGHT element writes all 5 digits (prep shrinks
// 19200 -> 3840 blocks); spikegen for ALL 50 steps appended (10,000 blocks).
// B1 layout (per fused1 LDS pinning): [nt:32][kc:26][s:5][lane:64][jj:16].
// B2 layout unchanged: [s:5][nt:4][kc:32][lane:64][jj:16].
// ---------------------------------------------------------------------------
__global__ __launch_bounds__(256) void setup_kernel(
    const float* __restrict__ W1, const float* __restrict__ W2,
    signed char* __restrict__ B1, signed char* __restrict__ B2,
    const float* __restrict__ x, i32x4* __restrict__ A) {
  if (blockIdx.x >= PREP_BLOCKS) {
    spike_block(x, A, 0, blockIdx.x - PREP_BLOCKS, threadIdx.x);
    return;
  }
  int idx = blockIdx.x * 256 + threadIdx.x;
  const int NB1 = 32 * 26 * 64 * 16;          // 851,968
  float w;
  signed char* dst;
  size_t stride;
  if (idx < NB1) {
    int jj = idx & 15;
    int lane = (idx >> 4) & 63;
    int kc = (idx >> 10) % 26;
    int nt = (idx >> 10) / 26;                // 0..31
    int k = kc * 32 + ((lane >> 5) << 4) + jj;
    int o = nt * 32 + (lane & 31);
    w = (o < 1000 && k < 784) ? W1[o * 784 + k] : 0.0f;
    dst = B1 + (size_t)(nt * 26 + kc) * 5120 + (lane << 4) + jj;
    stride = 1024;                            // s-stride within [kc] span
  } else {
    int m2 = idx - NB1;                       // < 131,072 (grid exact)
    int jj = m2 & 15;
    int lane = (m2 >> 4) & 63;
    int kc = (m2 >> 10) & 31;
    int nt = (m2 >> 10) >> 5;                 // 0..3
    int k = kc * 32 + ((lane >> 5) << 4) + jj;
    int o = nt * 32 + (lane & 31);
    w = (o < 100 && k < 1000) ? W2[o * 1000 + k] : 0.0f;
    dst = B2 + (size_t)(nt * 32 + kc) * 1024 + (lane << 4) + jj;
    stride = 4 * 32 * 1024;                   // s-stride (old layout)
  }
  long long V = llrint((double)w * 281474976710656.0);   // w * 2^48, exact
  signed char d = (signed char)(V & 0xFF);
  V = (V - (long long)d) >> 8;                // drop digit 0 (err <= 2^-41)
#pragma unroll
  for (int s = 0; s < 5; ++s) {
    d = (signed char)(V & 0xFF);
    V = (V - (long long)d) >> 8;
    dst[(size_t)s * stride] = d;
  }
}

// ---------------------------------------------------------------------------
// fused1: GEMM1 + layer-1 recurrence, all 50 steps in one dispatch.
// 256 blocks (id = nt*8 + mtg, XCD = id%8 = mtg) x 4 waves; wave owns tile
// (mt = mtg*4+wv, nt): 16 membranes (f64) + spike mask in regs for the whole
// run. Slices 0..3 of B pinned in 100 KB dynamic LDS (loaded once, ONE
// barrier total); slice 4 + A streamed from global, prefetch depth 2 with
// wrap into the next step. Dual accumulator banks: epilogue of step t-1
// interleaved into kc 0..15 of step t.
// ---------------------------------------------------------------------------
#define F1_EPI(CP, r) do {                                                    \
    long long T = (long long)CP[4][r];                                        \
    T = (T << 8) + (long long)CP[3][r];                                       \
    T = (T << 8) + (long long)CP[2][r];                                       \
    T = (T << 8) + (long long)CP[1][r];                                       \
    T = (T << 8) + (long long)CP[0][r];                                       \
    double I = (double)T * 0x1p-40;                                           \
    double mm = (((spk >> (r)) & 1u) ? 0.0 : m[r] * alpha) + I;               \
    m[r] = mm;                                                                \
    unsigned int sp = (mm >= 1.0) ? 1u : 0u;                                  \
    spk = (spk & ~(1u << (r))) | (sp << (r));                                 \
    hp[(size_t)(((r) & 3) + 8 * ((r) >> 2) + rb) * 1024] = (signed char)sp;   \
    CP[0][r] = 0; CP[1][r] = 0; CP[2][r] = 0; CP[3][r] = 0; CP[4][r] = 0;     \
  } while (0)

#define F1_PHASE(CC, CP, DOEPI) do {                                          \
    _Pragma("unroll")                                                         \
    for (int kc = 0; kc < 25; ++kc) {                                         \
      i32x4 b0 = blsv[(kc * 4 + 0) * 64 + lane];                              \
      i32x4 b1 = blsv[(kc * 4 + 1) * 64 + lane];                              \
      i32x4 b2 = blsv[(kc * 4 + 2) * 64 + lane];                              \
      i32x4 b3 = blsv[(kc * 4 + 3) * 64 + lane];                              \
      i32x4 av = a0, gv = g0;                                                 \
      a0 = a1; g0 = g1;                                                       \
      a1 = (kc + 2 < 25) ? Ap[(kc + 2) * 64]                                  \
                         : Ap[53248 + (kc + 2 - 25) * 64];                    \
      g1 = (kc + 2 < 25) ? Bg[((kc + 2) * 5 + 4) * 64]                        \
                         : Bg[((kc + 2 - 25) * 5 + 4) * 64];                  \
      CC[0] = __builtin_amdgcn_mfma_i32_32x32x32_i8(av, b0, CC[0], 0, 0, 0);  \
      CC[1] = __builtin_amdgcn_mfma_i32_32x32x32_i8(av, b1, CC[1], 0, 0, 0);  \
      CC[2] = __builtin_amdgcn_mfma_i32_32x32x32_i8(av, b2, CC[2], 0, 0, 0);  \
      CC[3] = __builtin_amdgcn_mfma_i32_32x32x32_i8(av, b3, CC[3], 0, 0, 0);  \
      CC[4] = __builtin_amdgcn_mfma_i32_32x32x32_i8(av, gv, CC[4], 0, 0, 0);  \
      if ((DOEPI) && kc < 16) F1_EPI(CP, kc);                                 \
    }                                                                         \
    Ap += 53248;                                                              \
    if (DOEPI) hp += 1048576;                                                 \
  } while (0)

__global__ __launch_bounds__(256, 1) void fused1_kernel(
    const signed char* __restrict__ B1, const i32x4* __restrict__ Afc,
    signed char* __restrict__ h1sc, const float* __restrict__ tau0) {
  extern __shared__ i32x4 blsv[];             // [25 kc][4 sl][64] = 102,400 B
  const int tid = threadIdx.x, lane = tid & 63, wv = tid >> 6;
  const int id = (int)blockIdx.x;
  const int mtg = id & 7, nt = id >> 3;       // XCD = id%8 = mtg (A-locality)
  const int mt = mtg * 4 + wv;
  const i32x4* B1v = (const i32x4*)B1;

  // one-time B pin: digit slices 0..3 of this nt -> LDS (6400 i32x4)
  for (int r = tid; r < 6400; r += 256) {
    int fi = r >> 6, l = r & 63;
    int kc = fi >> 2, s = fi & 3;
    blsv[r] = B1v[(size_t)nt * 8320 + (kc * 5 + s) * 64 + l];
  }

  const double alpha = 1.0 / (1.0 + exp(-(double)tau0[0]));
  double m[16];
  unsigned int spk = 0;
#pragma unroll
  for (int r = 0; r < 16; ++r) m[r] = 0.5;
  i32x16 CA[5], CB[5];
#pragma unroll
  for (int s = 0; s < 5; ++s)
#pragma unroll
    for (int i = 0; i < 16; ++i) { CA[s][i] = 0; CB[s][i] = 0; }

  const i32x4* Ap = Afc + (size_t)mt * 26 * 64 + lane;   // t-stride 53,248
  const i32x4* Bg = B1v + (size_t)nt * 8320 + lane;      // slice-4 stream
  const int rb = 4 * (lane >> 5);
  signed char* hp = h1sc + (size_t)(mt * 32) * 1024 + nt * 32 + (lane & 31);

  __syncthreads();                            // the ONLY barrier

  i32x4 a0 = Ap[0], a1 = Ap[64];
  i32x4 g0 = Bg[4 * 64], g1 = Bg[9 * 64];

  F1_PHASE(CA, CB, 0);                        // t = 0 (no epilogue yet)
#pragma unroll 1
  for (int tp = 0; tp < 24; ++tp) {
    F1_PHASE(CB, CA, 1);                      // t = 2tp+1, epi t = 2tp
    F1_PHASE(CA, CB, 1);                      // t = 2tp+2, epi t = 2tp+1
  }
  F1_PHASE(CB, CA, 1);                        // t = 49, epi t = 48
#pragma unroll
  for (int r = 0; r < 16; ++r) F1_EPI(CB, r); // epi t = 49
}

// ---------------------------------------------------------------------------
// GEMM2: M=50*1024, N=128, K=1024, 5 slices. A = h1sc bytes row-major.
// LDS-staged B (wave w stages slice w, wave 0 also slice 4), double-buffered.
// ---------------------------------------------------------------------------
__global__ __launch_bounds__(256, 3) void gemm2_kernel(
    const signed char* __restrict__ Bf, const signed char* __restrict__ h1sc,
    double* __restrict__ T2) {
  __shared__ i32x4 bls[2][NSL][64];
  int tid = threadIdx.x, lane = tid & 63, wv = tid >> 6;
  int nt = blockIdx.x & 3;             // 0..3
  int mg = blockIdx.x >> 2;
  int tl = mg >> 3;                    // 0..49
  int mt = ((mg & 7) << 2) + wv;
  const signed char* Arow =
      h1sc + ((size_t)tl * 1024 + mt * 32 + (lane & 31)) * 1024 + ((lane >> 5) << 4);
  const i32x4* Bp = (const i32x4*)Bf + lane;
  const bool st4 = (wv == 0);
#define B2_IDX(s, kc) ((size_t)(((s) * 4 + nt) * 32 + (kc)) * 64)

  i32x16 C[NSL];
#pragma unroll
  for (int s = 0; s < NSL; ++s)
#pragma unroll
    for (int i = 0; i < 16; ++i) C[s][i] = 0;

  i32x4 sa = Bp[B2_IDX(wv, 0)];
  i32x4 sb; if (st4) sb = Bp[B2_IDX(4, 0)];
  i32x4 a0 = *(const i32x4*)(Arow);
  i32x4 a1 = *(const i32x4*)(Arow + 32);
  i32x4 a2;
  bls[0][wv][lane] = sa;
  if (st4) bls[0][4][lane] = sb;
  sa = Bp[B2_IDX(wv, 1)];
  if (st4) sb = Bp[B2_IDX(4, 1)];
  __syncthreads();

  for (int kc = 0; kc < 32; ++kc) {
    const int cur = kc & 1, nxt = cur ^ 1;
    if (kc + 1 < 32) {
      bls[nxt][wv][lane] = sa;
      if (st4) bls[nxt][4][lane] = sb;
    }
    if (kc + 2 < 32) {
      sa = Bp[B2_IDX(wv, kc + 2)];
      if (st4) sb = Bp[B2_IDX(4, kc + 2)];
      a2 = *(const i32x4*)(Arow + (size_t)(kc + 2) * 32);
    }
    i32x4 b0 = bls[cur][0][lane], b1 = bls[cur][1][lane], b2 = bls[cur][2][lane];
    i32x4 b3 = bls[cur][3][lane], b4 = bls[cur][4][lane];
    C[0] = __builtin_amdgcn_mfma_i32_32x32x32_i8(a0, b0, C[0], 0, 0, 0);
    C[1] = __builtin_amdgcn_mfma_i32_32x32x32_i8(a0, b1, C[1], 0, 0, 0);
    C[2] = __builtin_amdgcn_mfma_i32_32x32x32_i8(a0, b2, C[2], 0, 0, 0);
    C[3] = __builtin_amdgcn_mfma_i32_32x32x32_i8(a0, b3, C[3], 0, 0, 0);
    C[4] = __builtin_amdgcn_mfma_i32_32x32x32_i8(a0, b4, C[4], 0, 0, 0);
    a0 = a1; a1 = a2;
    __syncthreads();
  }

  int o = nt * 32 + (lane & 31);
  int rb = 4 * (lane >> 5);
#pragma unroll
  for (int r = 0; r < 16; ++r) {
    int row = (r & 3) + 8 * (r >> 2) + rb;
    int b = mt * 32 + row;
    long long T = (long long)C[4][r];
    T = (T << 8) + (long long)C[3][r];
    T = (T << 8) + (long long)C[2][r];
    T = (T << 8) + (long long)C[1][r];
    T = (T << 8) + (long long)C[0][r];
    T2[((size_t)tl * 1024 + b) * 128 + o] = (double)T * 0x1p-40;
  }
}

// ---------------------------------------------------------------------------
// rec2: layer-2 membrane recurrence + AvgPool(10) + pPLI accumulator.
// ---------------------------------------------------------------------------
__global__ __launch_bounds__(256) void rec2_kernel(
    const double* __restrict__ T2, double* __restrict__ h2m_st,
    signed char* __restrict__ h2s_st, double* __restrict__ acc_st,
    const float* __restrict__ tauv, const float* __restrict__ acct,
    int t0, int C, float* __restrict__ out) {
  __shared__ signed char sp[256];
  int tid = threadIdx.x;
  int b = blockIdx.x * 2 + (tid >> 7);
  int o = tid & 127;
  double alpha = 1.0 / (1.0 + exp(-(double)tauv[0]));
  double adec  = 1.0 / (1.0 + exp(-(double)acct[0]));
  double m, s, accv = 0.0;
  bool isPool = (o < 10);
  if (t0 == 0) {
    m = 0.5; s = 0.0;
  } else {
    m = h2m_st[(size_t)b * 128 + o];
    s = (double)h2s_st[(size_t)b * 128 + o];
    if (isPool) accv = acc_st[b * 10 + o];
  }
  for (int tl = 0; tl < C; ++tl) {
    double I = T2[((size_t)tl * 1024 + b) * 128 + o];
    m = (s != 0.0 ? 0.0 : m * alpha) + I;
    bool spk = (m - 1.0) >= 0.0;
    s = spk ? 1.0 : 0.0;
    sp[tid] = spk ? 1 : 0;
    __syncthreads();
    if (isPool) {
      int base = tid & 128;
      int isum = 0;
#pragma unroll
      for (int k = 0; k < 10; ++k) isum += sp[base + o * 10 + k];
      accv = accv * adec + (double)isum / 10.0;
      if (t0 + tl == NSTEPS - 1) out[b * 10 + o] = (float)accv;
    }
    __syncthreads();
  }
  h2m_st[(size_t)b * 128 + o] = m;
  h2s_st[(size_t)b * 128 + o] = (signed char)(s != 0.0 ? 1 : 0);
  if (isPool) acc_st[b * 10 + o] = accv;
}

// ---------------------------------------------------------------------------
extern "C" void kernel_launch(void* const* d_in, const int* in_sizes, int n_in,
                              void* d_out, int out_size, void* d_ws, size_t ws_size,
                              hipStream_t stream) {
  const float* x    = (const float*)d_in[0];
  const float* W1   = (const float*)d_in[1];
  const float* W2   = (const float*)d_in[2];
  const float* tau0 = (const float*)d_in[3];
  const float* tauv = (const float*)d_in[4];
  const float* acct = (const float*)d_in[5];
  float* out = (float*)d_out;
  char*  ws  = (char*)d_ws;

  signed char* B1     = (signed char*)(ws + OFF_B1);
  signed char* B2     = (signed char*)(ws + OFF_B2);
  signed char* Af     = (signed char*)(ws + OFF_AF);
  signed char* h1sc   = (signed char*)(ws + OFF_H1SC);
  double*      T2     = (double*)(ws + OFF_T2);
  double*      h2m_st = (double*)(ws + OFF_H2M);
  signed char* h2s_st = (signed char*)(ws + OFF_H2S);
  double*      acc_st = (double*)(ws + OFF_ACC);
  i32x4*       Afv    = (i32x4*)Af;

  // opt-in to 100 KB dynamic LDS for fused1 (host-side, graph-capture-safe)
  static bool attr_done = false;
  if (!attr_done) {
    (void)hipFuncSetAttribute((const void*)fused1_kernel,
                              hipFuncAttributeMaxDynamicSharedMemorySize,
                              102400);
    attr_done = true;
  }

  // 1) weight digit prep (3840 blocks) + spikegen for ALL 50 steps (10,000)
  setup_kernel<<<PREP_BLOCKS + NSTEPS * 200, 256, 0, stream>>>(
      W1, W2, B1, B2, x, Afv);

  // 2) time-fused layer 1: all 50 steps, membranes register-resident
  fused1_kernel<<<256, 256, 102400, stream>>>(B1, Afv, h1sc, tau0);

  // 3) layer 2 GEMM over all 50 steps
  gemm2_kernel<<<4 * NSTEPS * 8, 256, 0, stream>>>(B2, h1sc, T2);

  // 4) layer 2 recurrence + pooling + accumulator
  rec2_kernel<<<512, 256, 0, stream>>>(
      T2, h2m_st, h2s_st, acc_st, tauv, acct, 0, NSTEPS, out);
}

// Round 2
// 1043.355 us; speedup vs baseline: 1.2436x; 1.2436x over previous
//
#include <hip/hip_runtime.h>
#include <hip/hip_bf16.h>
#include <math.h>

// ---------------------------------------------------------------------------
// sMLP4 round 12: TIME-FUSED layer 1, spill-free rebuild.
// Round-11 post-mortem: dual-bank acc (160 AGPR) + interleaved int64-Horner
// epilogue + two global prefetch streams => VGPR saturation (256) => per-step
// scratch spill (~1.6 GB HBM traffic == measured FETCH) => 1120us, MfmaUtil<1%.
// Fixes:
//   (1) single acc bank CA[5] (80 AGPR); epilogue BETWEEN steps;
//   (2) epilogue Horner in EXACT f64 (|C_s|<2^24, every t*256+C integer
//       < 2^47 => exact; bit-identical to int64 path, tiny live range);
//   (3) ALL 5 digit slices pinned in 128,000 B LDS (loaded once, ONE
//       barrier); only A streams from global (ring-4, next-step loads
//       issued before epilogue so epilogue hides the latency);
//   (4) B-frag LDS reads ring-2 prefetched (1 wave/SIMD can't hide 120cyc);
//   (5) kc==0 MFMAs take a hoisted zero C-in (no acc re-zeroing).
// Budget: LDS wall 25kc*20 b128*12cyc = 6000 cyc/step/CU, MFMA 4350, epi
// ~900 => ~144us. Trajectory bit-identical to round 10.
// ---------------------------------------------------------------------------

#define NSTEPS 50
#define KC1 25                     // real K chunks for layer 1 (800 >= 784)
#define NSL 5                      // digit slices (digits 1..5 of 2^48 fix-pt)

typedef __attribute__((ext_vector_type(4)))  int i32x4;
typedef __attribute__((ext_vector_type(16))) int i32x16;

// fixed workspace layout (bytes, all 256-aligned)
#define OFF_B1     0ull            // i8 [32*26*5*64*16] = 4,259,840
#define OFF_B2     4259840ull      // i8 [5*4*32*1024]   =   655,360
#define OFF_AF     4915200ull      // i8 [50*32*26*64*16]= 42,598,400
#define OFF_H1SC   47513600ull     // i8 [50*1024*1024]  = 52,428,800
#define OFF_T2     99942400ull     // f64[50*1024*128]   = 52,428,800
#define OFF_H2M    152371200ull    // f64[1024*128]      = 1,048,576
#define OFF_H2S    153419776ull    // i8 [1024*128]      =   131,072
#define OFF_ACC    153550848ull    // f64[1024*10]       =    81,920
#define WS_END     153632768ull    // 146.5 MB

#define PREP_BLOCKS 3840           // (851,968 + 131,072) / 256

// ---------------------------------------------------------------------------
// threefry2x32, key (0,42), partitionable mode: bits(i) = x0^x1 on ctr (0,i)
// ---------------------------------------------------------------------------
__device__ __forceinline__ unsigned int rotl32(unsigned int v, int d) {
#if __has_builtin(__builtin_amdgcn_alignbit)
  return __builtin_amdgcn_alignbit(v, v, (unsigned int)(32 - d));
#else
  return (v << d) | (v >> (32 - d));
#endif
}

__device__ __forceinline__ unsigned int tf_bits(unsigned int i) {
  const unsigned int ks0 = 0u;
  const unsigned int ks1 = 42u;
  const unsigned int ks2 = 0x1BD11BDAu ^ 0u ^ 42u;
  unsigned int x0 = 0u + ks0;
  unsigned int x1 = i + ks1;
#define TF_RND(r) { x0 += x1; x1 = rotl32(x1, r); x1 ^= x0; }
  TF_RND(13) TF_RND(15) TF_RND(26) TF_RND(6)
  x0 += ks1; x1 += ks2 + 1u;
  TF_RND(17) TF_RND(29) TF_RND(16) TF_RND(24)
  x0 += ks2; x1 += ks0 + 2u;
  TF_RND(13) TF_RND(15) TF_RND(26) TF_RND(6)
  x0 += ks0; x1 += ks1 + 3u;
  TF_RND(17) TF_RND(29) TF_RND(16) TF_RND(24)
  x0 += ks1; x1 += ks2 + 4u;
  TF_RND(13) TF_RND(15) TF_RND(26) TF_RND(6)
  x0 += ks2; x1 += ks0 + 5u;
#undef TF_RND
  return x0 ^ x1;
}

// ---------------------------------------------------------------------------
// spikegen role (one block = 4 waves = 4 (t,mt,kc) groups).
// A-frag: lane holds A[m = mt*32+(lane&31)][k = kc*32+(lane>>5)*16+jj].
// Integer compare: u < x  <=>  (bits>>9) < ceil(x*2^23)   (both exact).
// ---------------------------------------------------------------------------
__device__ __forceinline__ void spike_block(
    const float* __restrict__ x, i32x4* __restrict__ A, int t0, int gblk,
    int tid) {
  int g = gblk * 4 + (tid >> 6);
  int lane = tid & 63;
  int kc = g % 25;
  int r = g / 25;                     // tl*32 + mt
  int mt = r & 31;
  int t = t0 + (r >> 5);
  int b = mt * 32 + (lane & 31);
  int j0 = kc * 32 + ((lane >> 5) << 4);
  unsigned int wds[4] = {0u, 0u, 0u, 0u};
  if (j0 < 784) {                     // 784 = 49*16: wave-uniform guard
    unsigned int base = (unsigned int)(t * 1024 + b) * 784u + (unsigned int)j0;
    const float* xp = x + b * 784 + j0;
#pragma unroll
    for (int q = 0; q < 4; ++q) {
      float4 xv = *(const float4*)(xp + 4 * q);
      unsigned int K0 = (unsigned int)(int)ceilf(xv.x * 8388608.0f);
      unsigned int K1 = (unsigned int)(int)ceilf(xv.y * 8388608.0f);
      unsigned int K2 = (unsigned int)(int)ceilf(xv.z * 8388608.0f);
      unsigned int K3 = (unsigned int)(int)ceilf(xv.w * 8388608.0f);
      unsigned int w4 = 0u;
      if ((tf_bits(base + 4 * q + 0) >> 9) < K0) w4 |= 1u;
      if ((tf_bits(base + 4 * q + 1) >> 9) < K1) w4 |= 1u << 8;
      if ((tf_bits(base + 4 * q + 2) >> 9) < K2) w4 |= 1u << 16;
      if ((tf_bits(base + 4 * q + 3) >> 9) < K3) w4 |= 1u << 24;
      wds[q] = w4;
    }
  }
  i32x4 v;
  v.x = (int)wds[0]; v.y = (int)wds[1]; v.z = (int)wds[2]; v.w = (int)wds[3];
  A[(size_t)(((t * 32 + mt) * 26) + kc) * 64 + lane] = v;
}

// ---------------------------------------------------------------------------
// setup: one thread per WEIGHT element writes all 5 digits; spikegen for ALL
// 50 steps appended (10,000 blocks).
// B1 layout: [nt:32][kc:26][s:5][lane:64][jj:16]  (per-nt span contiguous,
// kc-major => fused1's 5-slice LDS pin is a straight 128,000 B copy).
// B2 layout: [s:5][nt:4][kc:32][lane:64][jj:16].
// ---------------------------------------------------------------------------
__global__ __launch_bounds__(256) void setup_kernel(
    const float* __restrict__ W1, const float* __restrict__ W2,
    signed char* __restrict__ B1, signed char* __restrict__ B2,
    const float* __restrict__ x, i32x4* __restrict__ A) {
  if (blockIdx.x >= PREP_BLOCKS) {
    spike_block(x, A, 0, blockIdx.x - PREP_BLOCKS, threadIdx.x);
    return;
  }
  int idx = blockIdx.x * 256 + threadIdx.x;
  const int NB1 = 32 * 26 * 64 * 16;          // 851,968
  float w;
  signed char* dst;
  size_t stride;
  if (idx < NB1) {
    int jj = idx & 15;
    int lane = (idx >> 4) & 63;
    int kc = (idx >> 10) % 26;
    int nt = (idx >> 10) / 26;                // 0..31
    int k = kc * 32 + ((lane >> 5) << 4) + jj;
    int o = nt * 32 + (lane & 31);
    w = (o < 1000 && k < 784) ? W1[o * 784 + k] : 0.0f;
    dst = B1 + (size_t)(nt * 26 + kc) * 5120 + (lane << 4) + jj;
    stride = 1024;                            // s-stride within [kc] span
  } else {
    int m2 = idx - NB1;                       // < 131,072 (grid exact)
    int jj = m2 & 15;
    int lane = (m2 >> 4) & 63;
    int kc = (m2 >> 10) & 31;
    int nt = (m2 >> 10) >> 5;                 // 0..3
    int k = kc * 32 + ((lane >> 5) << 4) + jj;
    int o = nt * 32 + (lane & 31);
    w = (o < 100 && k < 1000) ? W2[o * 1000 + k] : 0.0f;
    dst = B2 + (size_t)(nt * 32 + kc) * 1024 + (lane << 4) + jj;
    stride = 4 * 32 * 1024;                   // s-stride (old layout)
  }
  long long V = llrint((double)w * 281474976710656.0);   // w * 2^48, exact
  signed char d = (signed char)(V & 0xFF);
  V = (V - (long long)d) >> 8;                // drop digit 0 (err <= 2^-41)
#pragma unroll
  for (int s = 0; s < 5; ++s) {
    d = (signed char)(V & 0xFF);
    V = (V - (long long)d) >> 8;
    dst[(size_t)s * stride] = d;
  }
}

// ---------------------------------------------------------------------------
// fused1: GEMM1 + layer-1 recurrence, all 50 steps in one dispatch.
// 256 blocks (id = nt*8 + mtg, XCD = id%8 = mtg => same-XCD blocks share the
// same 4-mt A stream, L2-resident window) x 4 waves; wave owns tile
// (mt = mtg*4+wv, nt). All 5 B digit slices pinned in 128,000 B LDS (one
// barrier total). Single acc bank CA[5]; per-step epilogue: exact f64
// Horner (t*256+C integer < 2^47 => exact == int64 path), membrane update,
// spike byte out. A: global ring-4, next-step loads issued before epilogue.
// B-frags: LDS ring-2.
// ---------------------------------------------------------------------------
#define F1_EPI_R(r) do {                                                      \
    double td = (double)CA[4][r];                                             \
    td = td * 256.0 + (double)CA[3][r];                                       \
    td = td * 256.0 + (double)CA[2][r];                                       \
    td = td * 256.0 + (double)CA[1][r];                                       \
    td = td * 256.0 + (double)CA[0][r];                                       \
    double I = td * 0x1p-40;                                                  \
    double mm = (((spk >> (r)) & 1u) ? 0.0 : m[r] * alpha) + I;               \
    m[r] = mm;                                                                \
    unsigned int sp = ((mm - 1.0) >= 0.0) ? 1u : 0u;                          \
    spk = (spk & ~(1u << (r))) | (sp << (r));                                 \
    hp[(size_t)(((r) & 3) + 8 * ((r) >> 2) + rb) * 1024] = (signed char)sp;   \
  } while (0)

__global__ __launch_bounds__(256, 1) void fused1_kernel(
    const signed char* __restrict__ B1, const i32x4* __restrict__ Afc,
    signed char* __restrict__ h1sc, const float* __restrict__ tau0) {
  extern __shared__ i32x4 blsv[];             // [25 kc][5 sl][64] = 128,000 B
  const int tid = threadIdx.x, lane = tid & 63, wv = tid >> 6;
  const int id = (int)blockIdx.x;
  const int mtg = id & 7, nt = id >> 3;       // XCD = id%8 = mtg (A-locality)
  const int mt = mtg * 4 + wv;
  const i32x4* B1v = (const i32x4*)B1;

  // one-time B pin: all 5 digit slices of this nt -> LDS (8000 i32x4,
  // contiguous copy: B1 is [kc][s][lane][16] within the nt span)
  for (int r = tid; r < 8000; r += 256)
    blsv[r] = B1v[(size_t)nt * 8320 + r];

  const double alpha = 1.0 / (1.0 + exp(-(double)tau0[0]));
  double m[16];
  unsigned int spk = 0;
#pragma unroll
  for (int r = 0; r < 16; ++r) m[r] = 0.5;

  i32x16 Z;                                   // hoisted zero C-in for kc==0
#pragma unroll
  for (int i = 0; i < 16; ++i) Z[i] = 0;
  i32x16 CA[5];

  const i32x4* At = Afc + (size_t)mt * 26 * 64 + lane;   // t-stride 53,248
  const int rb = 4 * (lane >> 5);
  signed char* hp = h1sc + (size_t)(mt * 32) * 1024 + nt * 32 + (lane & 31);

  // prologue A ring (t=0, kc 0..3) -- independent of LDS, issue pre-barrier
  i32x4 aR[4];
  aR[0] = At[0]; aR[1] = At[64]; aR[2] = At[128]; aR[3] = At[192];

  __syncthreads();                            // the ONLY barrier

  // prologue B ring (kc 0, 1)
  i32x4 bR[2][5];
#pragma unroll
  for (int s = 0; s < 5; ++s) {
    bR[0][s] = blsv[(0 * 5 + s) * 64 + lane];
    bR[1][s] = blsv[(1 * 5 + s) * 64 + lane];
  }

#pragma unroll 1
  for (int t = 0; t < NSTEPS; ++t) {
#pragma unroll
    for (int kc = 0; kc < 25; ++kc) {
      i32x4 av = aR[kc & 3];
      if (kc + 4 < 25) aR[kc & 3] = At[(kc + 4) * 64];
      i32x4 q0 = bR[kc & 1][0], q1 = bR[kc & 1][1], q2 = bR[kc & 1][2],
            q3 = bR[kc & 1][3], q4 = bR[kc & 1][4];
      if (kc + 2 < 25) {
#pragma unroll
        for (int s = 0; s < 5; ++s)
          bR[kc & 1][s] = blsv[((kc + 2) * 5 + s) * 64 + lane];
      }
      if (kc == 0) {
        CA[0] = __builtin_amdgcn_mfma_i32_32x32x32_i8(av, q0, Z, 0, 0, 0);
        CA[1] = __builtin_amdgcn_mfma_i32_32x32x32_i8(av, q1, Z, 0, 0, 0);
        CA[2] = __builtin_amdgcn_mfma_i32_32x32x32_i8(av, q2, Z, 0, 0, 0);
        CA[3] = __builtin_amdgcn_mfma_i32_32x32x32_i8(av, q3, Z, 0, 0, 0);
        CA[4] = __builtin_amdgcn_mfma_i32_32x32x32_i8(av, q4, Z, 0, 0, 0);
      } else {
        CA[0] = __builtin_amdgcn_mfma_i32_32x32x32_i8(av, q0, CA[0], 0, 0, 0);
        CA[1] = __builtin_amdgcn_mfma_i32_32x32x32_i8(av, q1, CA[1], 0, 0, 0);
        CA[2] = __builtin_amdgcn_mfma_i32_32x32x32_i8(av, q2, CA[2], 0, 0, 0);
        CA[3] = __builtin_amdgcn_mfma_i32_32x32x32_i8(av, q3, CA[3], 0, 0, 0);
        CA[4] = __builtin_amdgcn_mfma_i32_32x32x32_i8(av, q4, CA[4], 0, 0, 0);
      }
    }
    // next-step prefetch, issued BEFORE the epilogue so the ~900cyc of f64
    // work hides the load latency
    if (t + 1 < NSTEPS) At += 53248;
    aR[0] = At[0]; aR[1] = At[64]; aR[2] = At[128]; aR[3] = At[192];
#pragma unroll
    for (int s = 0; s < 5; ++s) {
      bR[0][s] = blsv[(0 * 5 + s) * 64 + lane];
      bR[1][s] = blsv[(1 * 5 + s) * 64 + lane];
    }
    // per-step epilogue: exact f64 Horner + pPLIF update + spike byte
#pragma unroll
    for (int r = 0; r < 16; ++r) F1_EPI_R(r);
    hp += 1048576;
  }
}

// ---------------------------------------------------------------------------
// GEMM2: M=50*1024, N=128, K=1024, 5 slices. A = h1sc bytes row-major.
// LDS-staged B (wave w stages slice w, wave 0 also slice 4), double-buffered.
// ---------------------------------------------------------------------------
__global__ __launch_bounds__(256, 3) void gemm2_kernel(
    const signed char* __restrict__ Bf, const signed char* __restrict__ h1sc,
    double* __restrict__ T2) {
  __shared__ i32x4 bls[2][NSL][64];
  int tid = threadIdx.x, lane = tid & 63, wv = tid >> 6;
  int nt = blockIdx.x & 3;             // 0..3
  int mg = blockIdx.x >> 2;
  int tl = mg >> 3;                    // 0..49
  int mt = ((mg & 7) << 2) + wv;
  const signed char* Arow =
      h1sc + ((size_t)tl * 1024 + mt * 32 + (lane & 31)) * 1024 + ((lane >> 5) << 4);
  const i32x4* Bp = (const i32x4*)Bf + lane;
  const bool st4 = (wv == 0);
#define B2_IDX(s, kc) ((size_t)(((s) * 4 + nt) * 32 + (kc)) * 64)

  i32x16 C[NSL];
#pragma unroll
  for (int s = 0; s < NSL; ++s)
#pragma unroll
    for (int i = 0; i < 16; ++i) C[s][i] = 0;

  i32x4 sa = Bp[B2_IDX(wv, 0)];
  i32x4 sb; if (st4) sb = Bp[B2_IDX(4, 0)];
  i32x4 a0 = *(const i32x4*)(Arow);
  i32x4 a1 = *(const i32x4*)(Arow + 32);
  i32x4 a2;
  bls[0][wv][lane] = sa;
  if (st4) bls[0][4][lane] = sb;
  sa = Bp[B2_IDX(wv, 1)];
  if (st4) sb = Bp[B2_IDX(4, 1)];
  __syncthreads();

  for (int kc = 0; kc < 32; ++kc) {
    const int cur = kc & 1, nxt = cur ^ 1;
    if (kc + 1 < 32) {
      bls[nxt][wv][lane] = sa;
      if (st4) bls[nxt][4][lane] = sb;
    }
    if (kc + 2 < 32) {
      sa = Bp[B2_IDX(wv, kc + 2)];
      if (st4) sb = Bp[B2_IDX(4, kc + 2)];
      a2 = *(const i32x4*)(Arow + (size_t)(kc + 2) * 32);
    }
    i32x4 b0 = bls[cur][0][lane], b1 = bls[cur][1][lane], b2 = bls[cur][2][lane];
    i32x4 b3 = bls[cur][3][lane], b4 = bls[cur][4][lane];
    C[0] = __builtin_amdgcn_mfma_i32_32x32x32_i8(a0, b0, C[0], 0, 0, 0);
    C[1] = __builtin_amdgcn_mfma_i32_32x32x32_i8(a0, b1, C[1], 0, 0, 0);
    C[2] = __builtin_amdgcn_mfma_i32_32x32x32_i8(a0, b2, C[2], 0, 0, 0);
    C[3] = __builtin_amdgcn_mfma_i32_32x32x32_i8(a0, b3, C[3], 0, 0, 0);
    C[4] = __builtin_amdgcn_mfma_i32_32x32x32_i8(a0, b4, C[4], 0, 0, 0);
    a0 = a1; a1 = a2;
    __syncthreads();
  }

  int o = nt * 32 + (lane & 31);
  int rb = 4 * (lane >> 5);
#pragma unroll
  for (int r = 0; r < 16; ++r) {
    int row = (r & 3) + 8 * (r >> 2) + rb;
    int b = mt * 32 + row;
    long long T = (long long)C[4][r];
    T = (T << 8) + (long long)C[3][r];
    T = (T << 8) + (long long)C[2][r];
    T = (T << 8) + (long long)C[1][r];
    T = (T << 8) + (long long)C[0][r];
    T2[((size_t)tl * 1024 + b) * 128 + o] = (double)T * 0x1p-40;
  }
}

// ---------------------------------------------------------------------------
// rec2: layer-2 membrane recurrence + AvgPool(10) + pPLI accumulator.
// ---------------------------------------------------------------------------
__global__ __launch_bounds__(256) void rec2_kernel(
    const double* __restrict__ T2, double* __restrict__ h2m_st,
    signed char* __restrict__ h2s_st, double* __restrict__ acc_st,
    const float* __restrict__ tauv, const float* __restrict__ acct,
    int t0, int C, float* __restrict__ out) {
  __shared__ signed char sp[256];
  int tid = threadIdx.x;
  int b = blockIdx.x * 2 + (tid >> 7);
  int o = tid & 127;
  double alpha = 1.0 / (1.0 + exp(-(double)tauv[0]));
  double adec  = 1.0 / (1.0 + exp(-(double)acct[0]));
  double m, s, accv = 0.0;
  bool isPool = (o < 10);
  if (t0 == 0) {
    m = 0.5; s = 0.0;
  } else {
    m = h2m_st[(size_t)b * 128 + o];
    s = (double)h2s_st[(size_t)b * 128 + o];
    if (isPool) accv = acc_st[b * 10 + o];
  }
  for (int tl = 0; tl < C; ++tl) {
    double I = T2[((size_t)tl * 1024 + b) * 128 + o];
    m = (s != 0.0 ? 0.0 : m * alpha) + I;
    bool spk = (m - 1.0) >= 0.0;
    s = spk ? 1.0 : 0.0;
    sp[tid] = spk ? 1 : 0;
    __syncthreads();
    if (isPool) {
      int base = tid & 128;
      int isum = 0;
#pragma unroll
      for (int k = 0; k < 10; ++k) isum += sp[base + o * 10 + k];
      accv = accv * adec + (double)isum / 10.0;
      if (t0 + tl == NSTEPS - 1) out[b * 10 + o] = (float)accv;
    }
    __syncthreads();
  }
  h2m_st[(size_t)b * 128 + o] = m;
  h2s_st[(size_t)b * 128 + o] = (signed char)(s != 0.0 ? 1 : 0);
  if (isPool) acc_st[b * 10 + o] = accv;
}

// ---------------------------------------------------------------------------
extern "C" void kernel_launch(void* const* d_in, const int* in_sizes, int n_in,
                              void* d_out, int out_size, void* d_ws, size_t ws_size,
                              hipStream_t stream) {
  const float* x    = (const float*)d_in[0];
  const float* W1   = (const float*)d_in[1];
  const float* W2   = (const float*)d_in[2];
  const float* tau0 = (const float*)d_in[3];
  const float* tauv = (const float*)d_in[4];
  const float* acct = (const float*)d_in[5];
  float* out = (float*)d_out;
  char*  ws  = (char*)d_ws;

  signed char* B1     = (signed char*)(ws + OFF_B1);
  signed char* B2     = (signed char*)(ws + OFF_B2);
  signed char* Af     = (signed char*)(ws + OFF_AF);
  signed char* h1sc   = (signed char*)(ws + OFF_H1SC);
  double*      T2     = (double*)(ws + OFF_T2);
  double*      h2m_st = (double*)(ws + OFF_H2M);
  signed char* h2s_st = (signed char*)(ws + OFF_H2S);
  double*      acc_st = (double*)(ws + OFF_ACC);
  i32x4*       Afv    = (i32x4*)Af;

  // opt-in to 128,000 B dynamic LDS for fused1 (host-side, capture-safe)
  static bool attr_done = false;
  if (!attr_done) {
    (void)hipFuncSetAttribute((const void*)fused1_kernel,
                              hipFuncAttributeMaxDynamicSharedMemorySize,
                              128000);
    attr_done = true;
  }

  // 1) weight digit prep (3840 blocks) + spikegen for ALL 50 steps (10,000)
  setup_kernel<<<PREP_BLOCKS + NSTEPS * 200, 256, 0, stream>>>(
      W1, W2, B1, B2, x, Afv);

  // 2) time-fused layer 1: all 50 steps, membranes register-resident
  fused1_kernel<<<256, 256, 128000, stream>>>(B1, Afv, h1sc, tau0);

  // 3) layer 2 GEMM over all 50 steps
  gemm2_kernel<<<4 * NSTEPS * 8, 256, 0, stream>>>(B2, h1sc, T2);

  // 4) layer 2 recurrence + pooling + accumulator
  rec2_kernel<<<512, 256, 0, stream>>>(
      T2, h2m_st, h2s_st, acc_st, tauv, acct, 0, NSTEPS, out);
}

// Round 3
// 641.234 us; speedup vs baseline: 2.0235x; 1.6271x over previous
//
#include <hip/hip_runtime.h>
#include <hip/hip_bf16.h>
#include <math.h>

// ---------------------------------------------------------------------------
// sMLP4 round 13: TIME-FUSED layer 1 + XCD-group lockstep.
// Round-12 post-mortem: FETCH 820 MB with WRITE only +35 MB => not spill;
// it is the A stream read 32x per XCD with only ~40% L2 hits. The 32 blocks
// per XCD (same mtg => same A slice) DRIFT with no sync; the 5.3 MB slice
// exceeds the 4 MB L2, so the stream thrashes to LLC; ring-4 prefetch
// (4 KB in flight) at LLC latency caps each wave at ~1 kc / 1500+ cyc ==
// measured 16.8 us/step. Fixes:
//   (1) lockstep: every 5 steps, the 32 blocks of a group (id&7) arrive on a
//       per-(group,phase) AGENT-scope counter and spin (capped -> pure perf
//       hint, correctness never depends on it). All 256 blocks co-resident
//       (128 KB LDS => 1 block/CU, grid == #CU). Drift <= 1 interval =>
//       window ~2 MB < L2 => A fetched once per XCD (compulsory 42.6 MB).
//   (2) A prefetch ring 4 -> 8 (8 KB in flight/wave) covers L2-hit latency.
//   (3) B ring dropped (direct LDS reads) to pay for the deeper A ring.
// Predicted: fused1 FETCH 90-150 MB, dur 140-200 us, VGPR < 230.
// Trajectory bit-identical to round 10.
// ---------------------------------------------------------------------------

#define NSTEPS 50
#define KC1 25                     // real K chunks for layer 1 (800 >= 784)
#define NSL 5                      // digit slices (digits 1..5 of 2^48 fix-pt)
#define SYNC_EVERY 5               // lockstep interval (steps)

typedef __attribute__((ext_vector_type(4)))  int i32x4;
typedef __attribute__((ext_vector_type(16))) int i32x16;

// fixed workspace layout (bytes, all 256-aligned)
#define OFF_B1     0ull            // i8 [32*26*5*64*16] = 4,259,840
#define OFF_B2     4259840ull      // i8 [5*4*32*1024]   =   655,360
#define OFF_AF     4915200ull      // i8 [50*32*26*64*16]= 42,598,400
#define OFF_H1SC   47513600ull     // i8 [50*1024*1024]  = 52,428,800
#define OFF_T2     99942400ull     // f64[50*1024*128]   = 52,428,800
#define OFF_H2M    152371200ull    // f64[1024*128]      = 1,048,576
#define OFF_H2S    153419776ull    // i8 [1024*128]      =   131,072
#define OFF_ACC    153550848ull    // f64[1024*10]       =    81,920
#define OFF_BAR    153632768ull    // u32[128] lockstep counters
#define WS_END     153633280ull    // 146.5 MB

#define PREP_BLOCKS 3840           // (851,968 + 131,072) / 256

// ---------------------------------------------------------------------------
// threefry2x32, key (0,42), partitionable mode: bits(i) = x0^x1 on ctr (0,i)
// ---------------------------------------------------------------------------
__device__ __forceinline__ unsigned int rotl32(unsigned int v, int d) {
#if __has_builtin(__builtin_amdgcn_alignbit)
  return __builtin_amdgcn_alignbit(v, v, (unsigned int)(32 - d));
#else
  return (v << d) | (v >> (32 - d));
#endif
}

__device__ __forceinline__ unsigned int tf_bits(unsigned int i) {
  const unsigned int ks0 = 0u;
  const unsigned int ks1 = 42u;
  const unsigned int ks2 = 0x1BD11BDAu ^ 0u ^ 42u;
  unsigned int x0 = 0u + ks0;
  unsigned int x1 = i + ks1;
#define TF_RND(r) { x0 += x1; x1 = rotl32(x1, r); x1 ^= x0; }
  TF_RND(13) TF_RND(15) TF_RND(26) TF_RND(6)
  x0 += ks1; x1 += ks2 + 1u;
  TF_RND(17) TF_RND(29) TF_RND(16) TF_RND(24)
  x0 += ks2; x1 += ks0 + 2u;
  TF_RND(13) TF_RND(15) TF_RND(26) TF_RND(6)
  x0 += ks0; x1 += ks1 + 3u;
  TF_RND(17) TF_RND(29) TF_RND(16) TF_RND(24)
  x0 += ks1; x1 += ks2 + 4u;
  TF_RND(13) TF_RND(15) TF_RND(26) TF_RND(6)
  x0 += ks2; x1 += ks0 + 5u;
#undef TF_RND
  return x0 ^ x1;
}

// ---------------------------------------------------------------------------
// spikegen role (one block = 4 waves = 4 (t,mt,kc) groups).
// A-frag: lane holds A[m = mt*32+(lane&31)][k = kc*32+(lane>>5)*16+jj].
// Integer compare: u < x  <=>  (bits>>9) < ceil(x*2^23)   (both exact).
// ---------------------------------------------------------------------------
__device__ __forceinline__ void spike_block(
    const float* __restrict__ x, i32x4* __restrict__ A, int t0, int gblk,
    int tid) {
  int g = gblk * 4 + (tid >> 6);
  int lane = tid & 63;
  int kc = g % 25;
  int r = g / 25;                     // tl*32 + mt
  int mt = r & 31;
  int t = t0 + (r >> 5);
  int b = mt * 32 + (lane & 31);
  int j0 = kc * 32 + ((lane >> 5) << 4);
  unsigned int wds[4] = {0u, 0u, 0u, 0u};
  if (j0 < 784) {                     // 784 = 49*16: wave-uniform guard
    unsigned int base = (unsigned int)(t * 1024 + b) * 784u + (unsigned int)j0;
    const float* xp = x + b * 784 + j0;
#pragma unroll
    for (int q = 0; q < 4; ++q) {
      float4 xv = *(const float4*)(xp + 4 * q);
      unsigned int K0 = (unsigned int)(int)ceilf(xv.x * 8388608.0f);
      unsigned int K1 = (unsigned int)(int)ceilf(xv.y * 8388608.0f);
      unsigned int K2 = (unsigned int)(int)ceilf(xv.z * 8388608.0f);
      unsigned int K3 = (unsigned int)(int)ceilf(xv.w * 8388608.0f);
      unsigned int w4 = 0u;
      if ((tf_bits(base + 4 * q + 0) >> 9) < K0) w4 |= 1u;
      if ((tf_bits(base + 4 * q + 1) >> 9) < K1) w4 |= 1u << 8;
      if ((tf_bits(base + 4 * q + 2) >> 9) < K2) w4 |= 1u << 16;
      if ((tf_bits(base + 4 * q + 3) >> 9) < K3) w4 |= 1u << 24;
      wds[q] = w4;
    }
  }
  i32x4 v;
  v.x = (int)wds[0]; v.y = (int)wds[1]; v.z = (int)wds[2]; v.w = (int)wds[3];
  A[(size_t)(((t * 32 + mt) * 26) + kc) * 64 + lane] = v;
}

// ---------------------------------------------------------------------------
// setup: one thread per WEIGHT element writes all 5 digits; spikegen for ALL
// 50 steps appended (10,000 blocks). Block 0 also zeroes the lockstep bar.
// B1 layout: [nt:32][kc:26][s:5][lane:64][jj:16]  (per-nt span contiguous).
// B2 layout: [s:5][nt:4][kc:32][lane:64][jj:16].
// ---------------------------------------------------------------------------
__global__ __launch_bounds__(256) void setup_kernel(
    const float* __restrict__ W1, const float* __restrict__ W2,
    signed char* __restrict__ B1, signed char* __restrict__ B2,
    const float* __restrict__ x, i32x4* __restrict__ A,
    unsigned int* __restrict__ bar) {
  if (blockIdx.x >= PREP_BLOCKS) {
    spike_block(x, A, 0, blockIdx.x - PREP_BLOCKS, threadIdx.x);
    return;
  }
  if (blockIdx.x == 0 && threadIdx.x < 128) bar[threadIdx.x] = 0u;
  int idx = blockIdx.x * 256 + threadIdx.x;
  const int NB1 = 32 * 26 * 64 * 16;          // 851,968
  float w;
  signed char* dst;
  size_t stride;
  if (idx < NB1) {
    int jj = idx & 15;
    int lane = (idx >> 4) & 63;
    int kc = (idx >> 10) % 26;
    int nt = (idx >> 10) / 26;                // 0..31
    int k = kc * 32 + ((lane >> 5) << 4) + jj;
    int o = nt * 32 + (lane & 31);
    w = (o < 1000 && k < 784) ? W1[o * 784 + k] : 0.0f;
    dst = B1 + (size_t)(nt * 26 + kc) * 5120 + (lane << 4) + jj;
    stride = 1024;                            // s-stride within [kc] span
  } else {
    int m2 = idx - NB1;                       // < 131,072 (grid exact)
    int jj = m2 & 15;
    int lane = (m2 >> 4) & 63;
    int kc = (m2 >> 10) & 31;
    int nt = (m2 >> 10) >> 5;                 // 0..3
    int k = kc * 32 + ((lane >> 5) << 4) + jj;
    int o = nt * 32 + (lane & 31);
    w = (o < 100 && k < 1000) ? W2[o * 1000 + k] : 0.0f;
    dst = B2 + (size_t)(nt * 32 + kc) * 1024 + (lane << 4) + jj;
    stride = 4 * 32 * 1024;                   // s-stride (old layout)
  }
  long long V = llrint((double)w * 281474976710656.0);   // w * 2^48, exact
  signed char d = (signed char)(V & 0xFF);
  V = (V - (long long)d) >> 8;                // drop digit 0 (err <= 2^-41)
#pragma unroll
  for (int s = 0; s < 5; ++s) {
    d = (signed char)(V & 0xFF);
    V = (V - (long long)d) >> 8;
    dst[(size_t)s * stride] = d;
  }
}

// ---------------------------------------------------------------------------
// fused1: GEMM1 + layer-1 recurrence, all 50 steps in one dispatch.
// 256 blocks (id = nt*8 + mtg, XCD = id%8 = mtg) x 4 waves; wave owns tile
// (mt = mtg*4+wv, nt). All 5 B digit slices pinned in 128,000 B LDS. Single
// acc bank CA[5]; per-step epilogue: exact f64 Horner (integer < 2^47 =>
// exact == int64 path). A: global ring-8; next-step loads issued before the
// epilogue. Every SYNC_EVERY steps the 32 blocks of group (id&7) lockstep
// via a capped atomic barrier so the shared A stream stays L2-resident.
// ---------------------------------------------------------------------------
#define F1_EPI_R(r) do {                                                      \
    double td = (double)CA[4][r];                                             \
    td = td * 256.0 + (double)CA[3][r];                                       \
    td = td * 256.0 + (double)CA[2][r];                                       \
    td = td * 256.0 + (double)CA[1][r];                                       \
    td = td * 256.0 + (double)CA[0][r];                                       \
    double I = td * 0x1p-40;                                                  \
    double mm = (((spk >> (r)) & 1u) ? 0.0 : m[r] * alpha) + I;               \
    m[r] = mm;                                                                \
    unsigned int sp = ((mm - 1.0) >= 0.0) ? 1u : 0u;                          \
    spk = (spk & ~(1u << (r))) | (sp << (r));                                 \
    hp[(size_t)(((r) & 3) + 8 * ((r) >> 2) + rb) * 1024] = (signed char)sp;   \
  } while (0)

__global__ __launch_bounds__(256, 1) void fused1_kernel(
    const signed char* __restrict__ B1, const i32x4* __restrict__ Afc,
    signed char* __restrict__ h1sc, const float* __restrict__ tau0,
    unsigned int* __restrict__ bar) {
  extern __shared__ i32x4 blsv[];             // [25 kc][5 sl][64] = 128,000 B
  const int tid = threadIdx.x, lane = tid & 63, wv = tid >> 6;
  const int id = (int)blockIdx.x;
  const int mtg = id & 7, nt = id >> 3;       // XCD = id%8 = mtg (A-locality)
  const int mt = mtg * 4 + wv;
  const i32x4* B1v = (const i32x4*)B1;

  // one-time B pin: all 5 digit slices of this nt -> LDS (8000 i32x4,
  // contiguous copy: B1 is [kc][s][lane][16] within the nt span)
  for (int r = tid; r < 8000; r += 256)
    blsv[r] = B1v[(size_t)nt * 8320 + r];

  const double alpha = 1.0 / (1.0 + exp(-(double)tau0[0]));
  double m[16];
  unsigned int spk = 0;
#pragma unroll
  for (int r = 0; r < 16; ++r) m[r] = 0.5;

  i32x16 Z;                                   // hoisted zero C-in for kc==0
#pragma unroll
  for (int i = 0; i < 16; ++i) Z[i] = 0;
  i32x16 CA[5];

  const i32x4* At = Afc + (size_t)mt * 26 * 64 + lane;   // t-stride 53,248
  const int rb = 4 * (lane >> 5);
  signed char* hp = h1sc + (size_t)(mt * 32) * 1024 + nt * 32 + (lane & 31);

  // prologue A ring (t=0, kc 0..7) -- independent of LDS, issue pre-barrier
  i32x4 aR[8];
#pragma unroll
  for (int i = 0; i < 8; ++i) aR[i] = At[i * 64];

  __syncthreads();                            // LDS pin complete

#pragma unroll 1
  for (int t = 0; t < NSTEPS; ++t) {
#pragma unroll
    for (int kc = 0; kc < 25; ++kc) {
      i32x4 av = aR[kc & 7];
      if (kc + 8 < 25) aR[kc & 7] = At[(kc + 8) * 64];
      i32x4 q0 = blsv[(kc * 5 + 0) * 64 + lane];
      i32x4 q1 = blsv[(kc * 5 + 1) * 64 + lane];
      i32x4 q2 = blsv[(kc * 5 + 2) * 64 + lane];
      i32x4 q3 = blsv[(kc * 5 + 3) * 64 + lane];
      i32x4 q4 = blsv[(kc * 5 + 4) * 64 + lane];
      if (kc == 0) {
        CA[0] = __builtin_amdgcn_mfma_i32_32x32x32_i8(av, q0, Z, 0, 0, 0);
        CA[1] = __builtin_amdgcn_mfma_i32_32x32x32_i8(av, q1, Z, 0, 0, 0);
        CA[2] = __builtin_amdgcn_mfma_i32_32x32x32_i8(av, q2, Z, 0, 0, 0);
        CA[3] = __builtin_amdgcn_mfma_i32_32x32x32_i8(av, q3, Z, 0, 0, 0);
        CA[4] = __builtin_amdgcn_mfma_i32_32x32x32_i8(av, q4, Z, 0, 0, 0);
      } else {
        CA[0] = __builtin_amdgcn_mfma_i32_32x32x32_i8(av, q0, CA[0], 0, 0, 0);
        CA[1] = __builtin_amdgcn_mfma_i32_32x32x32_i8(av, q1, CA[1], 0, 0, 0);
        CA[2] = __builtin_amdgcn_mfma_i32_32x32x32_i8(av, q2, CA[2], 0, 0, 0);
        CA[3] = __builtin_amdgcn_mfma_i32_32x32x32_i8(av, q3, CA[3], 0, 0, 0);
        CA[4] = __builtin_amdgcn_mfma_i32_32x32x32_i8(av, q4, CA[4], 0, 0, 0);
      }
    }
    // next-step A prefetch: issued BEFORE the epilogue so the ~900cyc of
    // f64 work hides the load latency (ring-8 in flight across the barrier)
    if (t + 1 < NSTEPS) At += 53248;
#pragma unroll
    for (int i = 0; i < 8; ++i) aR[i] = At[i * 64];
    // per-step epilogue: exact f64 Horner + pPLIF update + spike byte
#pragma unroll
    for (int r = 0; r < 16; ++r) F1_EPI_R(r);
    hp += 1048576;
    // lockstep: keep the 32 blocks sharing this A stream (group id&7)
    // within one interval so the stream stays L2-resident. Capped spin:
    // pure performance hint, never a correctness dependency.
    if (((t + 1) % SYNC_EVERY) == 0 && (t + 1) < NSTEPS) {
      __syncthreads();
      if (tid == 0) {
        int ph = (t + 1) / SYNC_EVERY - 1;    // 0..8
        unsigned int* c = bar + (mtg << 4) + ph;
        __hip_atomic_fetch_add(c, 1u, __ATOMIC_RELAXED,
                               __HIP_MEMORY_SCOPE_AGENT);
        for (int spin = 0; spin < 20000; ++spin) {
          if (__hip_atomic_load(c, __ATOMIC_RELAXED,
                                __HIP_MEMORY_SCOPE_AGENT) >= 32u) break;
          __builtin_amdgcn_s_sleep(8);
        }
      }
      __syncthreads();
    }
  }
}

// ---------------------------------------------------------------------------
// GEMM2: M=50*1024, N=128, K=1024, 5 slices. A = h1sc bytes row-major.
// LDS-staged B (wave w stages slice w, wave 0 also slice 4), double-buffered.
// ---------------------------------------------------------------------------
__global__ __launch_bounds__(256, 3) void gemm2_kernel(
    const signed char* __restrict__ Bf, const signed char* __restrict__ h1sc,
    double* __restrict__ T2) {
  __shared__ i32x4 bls[2][NSL][64];
  int tid = threadIdx.x, lane = tid & 63, wv = tid >> 6;
  int nt = blockIdx.x & 3;             // 0..3
  int mg = blockIdx.x >> 2;
  int tl = mg >> 3;                    // 0..49
  int mt = ((mg & 7) << 2) + wv;
  const signed char* Arow =
      h1sc + ((size_t)tl * 1024 + mt * 32 + (lane & 31)) * 1024 + ((lane >> 5) << 4);
  const i32x4* Bp = (const i32x4*)Bf + lane;
  const bool st4 = (wv == 0);
#define B2_IDX(s, kc) ((size_t)(((s) * 4 + nt) * 32 + (kc)) * 64)

  i32x16 C[NSL];
#pragma unroll
  for (int s = 0; s < NSL; ++s)
#pragma unroll
    for (int i = 0; i < 16; ++i) C[s][i] = 0;

  i32x4 sa = Bp[B2_IDX(wv, 0)];
  i32x4 sb; if (st4) sb = Bp[B2_IDX(4, 0)];
  i32x4 a0 = *(const i32x4*)(Arow);
  i32x4 a1 = *(const i32x4*)(Arow + 32);
  i32x4 a2;
  bls[0][wv][lane] = sa;
  if (st4) bls[0][4][lane] = sb;
  sa = Bp[B2_IDX(wv, 1)];
  if (st4) sb = Bp[B2_IDX(4, 1)];
  __syncthreads();

  for (int kc = 0; kc < 32; ++kc) {
    const int cur = kc & 1, nxt = cur ^ 1;
    if (kc + 1 < 32) {
      bls[nxt][wv][lane] = sa;
      if (st4) bls[nxt][4][lane] = sb;
    }
    if (kc + 2 < 32) {
      sa = Bp[B2_IDX(wv, kc + 2)];
      if (st4) sb = Bp[B2_IDX(4, kc + 2)];
      a2 = *(const i32x4*)(Arow + (size_t)(kc + 2) * 32);
    }
    i32x4 b0 = bls[cur][0][lane], b1 = bls[cur][1][lane], b2 = bls[cur][2][lane];
    i32x4 b3 = bls[cur][3][lane], b4 = bls[cur][4][lane];
    C[0] = __builtin_amdgcn_mfma_i32_32x32x32_i8(a0, b0, C[0], 0, 0, 0);
    C[1] = __builtin_amdgcn_mfma_i32_32x32x32_i8(a0, b1, C[1], 0, 0, 0);
    C[2] = __builtin_amdgcn_mfma_i32_32x32x32_i8(a0, b2, C[2], 0, 0, 0);
    C[3] = __builtin_amdgcn_mfma_i32_32x32x32_i8(a0, b3, C[3], 0, 0, 0);
    C[4] = __builtin_amdgcn_mfma_i32_32x32x32_i8(a0, b4, C[4], 0, 0, 0);
    a0 = a1; a1 = a2;
    __syncthreads();
  }

  int o = nt * 32 + (lane & 31);
  int rb = 4 * (lane >> 5);
#pragma unroll
  for (int r = 0; r < 16; ++r) {
    int row = (r & 3) + 8 * (r >> 2) + rb;
    int b = mt * 32 + row;
    long long T = (long long)C[4][r];
    T = (T << 8) + (long long)C[3][r];
    T = (T << 8) + (long long)C[2][r];
    T = (T << 8) + (long long)C[1][r];
    T = (T << 8) + (long long)C[0][r];
    T2[((size_t)tl * 1024 + b) * 128 + o] = (double)T * 0x1p-40;
  }
}

// ---------------------------------------------------------------------------
// rec2: layer-2 membrane recurrence + AvgPool(10) + pPLI accumulator.
// ---------------------------------------------------------------------------
__global__ __launch_bounds__(256) void rec2_kernel(
    const double* __restrict__ T2, double* __restrict__ h2m_st,
    signed char* __restrict__ h2s_st, double* __restrict__ acc_st,
    const float* __restrict__ tauv, const float* __restrict__ acct,
    int t0, int C, float* __restrict__ out) {
  __shared__ signed char sp[256];
  int tid = threadIdx.x;
  int b = blockIdx.x * 2 + (tid >> 7);
  int o = tid & 127;
  double alpha = 1.0 / (1.0 + exp(-(double)tauv[0]));
  double adec  = 1.0 / (1.0 + exp(-(double)acct[0]));
  double m, s, accv = 0.0;
  bool isPool = (o < 10);
  if (t0 == 0) {
    m = 0.5; s = 0.0;
  } else {
    m = h2m_st[(size_t)b * 128 + o];
    s = (double)h2s_st[(size_t)b * 128 + o];
    if (isPool) accv = acc_st[b * 10 + o];
  }
  for (int tl = 0; tl < C; ++tl) {
    double I = T2[((size_t)tl * 1024 + b) * 128 + o];
    m = (s != 0.0 ? 0.0 : m * alpha) + I;
    bool spk = (m - 1.0) >= 0.0;
    s = spk ? 1.0 : 0.0;
    sp[tid] = spk ? 1 : 0;
    __syncthreads();
    if (isPool) {
      int base = tid & 128;
      int isum = 0;
#pragma unroll
      for (int k = 0; k < 10; ++k) isum += sp[base + o * 10 + k];
      accv = accv * adec + (double)isum / 10.0;
      if (t0 + tl == NSTEPS - 1) out[b * 10 + o] = (float)accv;
    }
    __syncthreads();
  }
  h2m_st[(size_t)b * 128 + o] = m;
  h2s_st[(size_t)b * 128 + o] = (signed char)(s != 0.0 ? 1 : 0);
  if (isPool) acc_st[b * 10 + o] = accv;
}

// ---------------------------------------------------------------------------
extern "C" void kernel_launch(void* const* d_in, const int* in_sizes, int n_in,
                              void* d_out, int out_size, void* d_ws, size_t ws_size,
                              hipStream_t stream) {
  const float* x    = (const float*)d_in[0];
  const float* W1   = (const float*)d_in[1];
  const float* W2   = (const float*)d_in[2];
  const float* tau0 = (const float*)d_in[3];
  const float* tauv = (const float*)d_in[4];
  const float* acct = (const float*)d_in[5];
  float* out = (float*)d_out;
  char*  ws  = (char*)d_ws;

  signed char* B1     = (signed char*)(ws + OFF_B1);
  signed char* B2     = (signed char*)(ws + OFF_B2);
  signed char* Af     = (signed char*)(ws + OFF_AF);
  signed char* h1sc   = (signed char*)(ws + OFF_H1SC);
  double*      T2     = (double*)(ws + OFF_T2);
  double*      h2m_st = (double*)(ws + OFF_H2M);
  signed char* h2s_st = (signed char*)(ws + OFF_H2S);
  double*      acc_st = (double*)(ws + OFF_ACC);
  unsigned int* bar   = (unsigned int*)(ws + OFF_BAR);
  i32x4*       Afv    = (i32x4*)Af;

  // opt-in to 128,000 B dynamic LDS for fused1 (host-side, capture-safe)
  static bool attr_done = false;
  if (!attr_done) {
    (void)hipFuncSetAttribute((const void*)fused1_kernel,
                              hipFuncAttributeMaxDynamicSharedMemorySize,
                              128000);
    attr_done = true;
  }

  // 1) weight digit prep (3840 blocks) + spikegen for ALL 50 steps (10,000)
  setup_kernel<<<PREP_BLOCKS + NSTEPS * 200, 256, 0, stream>>>(
      W1, W2, B1, B2, x, Afv, bar);

  // 2) time-fused layer 1: all 50 steps, membranes register-resident
  fused1_kernel<<<256, 256, 128000, stream>>>(B1, Afv, h1sc, tau0, bar);

  // 3) layer 2 GEMM over all 50 steps
  gemm2_kernel<<<4 * NSTEPS * 8, 256, 0, stream>>>(B2, h1sc, T2);

  // 4) layer 2 recurrence + pooling + accumulator
  rec2_kernel<<<512, 256, 0, stream>>>(
      T2, h2m_st, h2s_st, acc_st, tauv, acct, 0, NSTEPS, out);
}

// Round 5
// 599.024 us; speedup vs baseline: 2.1661x; 1.0705x over previous
//
#include <hip/hip_runtime.h>
#include <hip/hip_bf16.h>
#include <math.h>

// ---------------------------------------------------------------------------
// sMLP4 round 14b: TIME-FUSED layer 1, LDS-pipe diet + explicit rings.
// (Round-14 resubmission -- the bench died on container infra, no data.)
// Round-13 post-mortem: lockstep fixed traffic (FETCH 36 MB compulsory,
// 0 spill) but dur stuck at 439us: latency-bound at 1 wave/SIMD, ~840cyc/kc
// vs 183cyc MFMA. Cause: 20 b128/kc on the shared LDS pipe (4 waves x 5
// shared-B frags) + direct blsv->MFMA reads serialize [read, wait, mfma].
// Fixes:
//   (1) slices 3,4 stream from GLOBAL (ring-4; per-XCD set 1.6 MB =>
//       L2-hit; VMEM pipe was idle) -> LDS down to 12 b128/kc/CU (144cyc
//       < 183cyc MFMA wall);
//   (2) slices 0..2 stay LDS-pinned (76,800 B) with explicit ring-2
//       prefetch: loads for kc+2 issue before kc's MFMAs;
//   (3) step-boundary refills issue before the f64 epilogue (~900cyc VALU
//       covers them); s_sleep(2) spin granularity.
// All ring indices kc&N in fully-unrolled loop => compile-time (no scratch).
// Trajectory bit-identical to round 10.
// ---------------------------------------------------------------------------

#define NSTEPS 50
#define KC1 25                     // real K chunks for layer 1 (800 >= 784)
#define NSL 5                      // digit slices (digits 1..5 of 2^48 fix-pt)
#define SYNC_EVERY 5               // lockstep interval (steps)

typedef __attribute__((ext_vector_type(4)))  int i32x4;
typedef __attribute__((ext_vector_type(16))) int i32x16;

// fixed workspace layout (bytes, all 256-aligned)
#define OFF_B1     0ull            // i8 [32*26*5*64*16] = 4,259,840
#define OFF_B2     4259840ull      // i8 [5*4*32*1024]   =   655,360
#define OFF_AF     4915200ull      // i8 [50*32*26*64*16]= 42,598,400
#define OFF_H1SC   47513600ull     // i8 [50*1024*1024]  = 52,428,800
#define OFF_T2     99942400ull     // f64[50*1024*128]   = 52,428,800
#define OFF_H2M    152371200ull    // f64[1024*128]      = 1,048,576
#define OFF_H2S    153419776ull    // i8 [1024*128]      =   131,072
#define OFF_ACC    153550848ull    // f64[1024*10]       =    81,920
#define OFF_BAR    153632768ull    // u32[128] lockstep counters
#define WS_END     153633280ull    // 146.5 MB

#define PREP_BLOCKS 3840           // (851,968 + 131,072) / 256

// ---------------------------------------------------------------------------
// threefry2x32, key (0,42), partitionable mode: bits(i) = x0^x1 on ctr (0,i)
// ---------------------------------------------------------------------------
__device__ __forceinline__ unsigned int rotl32(unsigned int v, int d) {
#if __has_builtin(__builtin_amdgcn_alignbit)
  return __builtin_amdgcn_alignbit(v, v, (unsigned int)(32 - d));
#else
  return (v << d) | (v >> (32 - d));
#endif
}

__device__ __forceinline__ unsigned int tf_bits(unsigned int i) {
  const unsigned int ks0 = 0u;
  const unsigned int ks1 = 42u;
  const unsigned int ks2 = 0x1BD11BDAu ^ 0u ^ 42u;
  unsigned int x0 = 0u + ks0;
  unsigned int x1 = i + ks1;
#define TF_RND(r) { x0 += x1; x1 = rotl32(x1, r); x1 ^= x0; }
  TF_RND(13) TF_RND(15) TF_RND(26) TF_RND(6)
  x0 += ks1; x1 += ks2 + 1u;
  TF_RND(17) TF_RND(29) TF_RND(16) TF_RND(24)
  x0 += ks2; x1 += ks0 + 2u;
  TF_RND(13) TF_RND(15) TF_RND(26) TF_RND(6)
  x0 += ks0; x1 += ks1 + 3u;
  TF_RND(17) TF_RND(29) TF_RND(16) TF_RND(24)
  x0 += ks1; x1 += ks2 + 4u;
  TF_RND(13) TF_RND(15) TF_RND(26) TF_RND(6)
  x0 += ks2; x1 += ks0 + 5u;
#undef TF_RND
  return x0 ^ x1;
}

// ---------------------------------------------------------------------------
// spikegen role (one block = 4 waves = 4 (t,mt,kc) groups).
// A-frag: lane holds A[m = mt*32+(lane&31)][k = kc*32+(lane>>5)*16+jj].
// Integer compare: u < x  <=>  (bits>>9) < ceil(x*2^23)   (both exact).
// ---------------------------------------------------------------------------
__device__ __forceinline__ void spike_block(
    const float* __restrict__ x, i32x4* __restrict__ A, int t0, int gblk,
    int tid) {
  int g = gblk * 4 + (tid >> 6);
  int lane = tid & 63;
  int kc = g % 25;
  int r = g / 25;                     // tl*32 + mt
  int mt = r & 31;
  int t = t0 + (r >> 5);
  int b = mt * 32 + (lane & 31);
  int j0 = kc * 32 + ((lane >> 5) << 4);
  unsigned int wds[4] = {0u, 0u, 0u, 0u};
  if (j0 < 784) {                     // 784 = 49*16: wave-uniform guard
    unsigned int base = (unsigned int)(t * 1024 + b) * 784u + (unsigned int)j0;
    const float* xp = x + b * 784 + j0;
#pragma unroll
    for (int q = 0; q < 4; ++q) {
      float4 xv = *(const float4*)(xp + 4 * q);
      unsigned int K0 = (unsigned int)(int)ceilf(xv.x * 8388608.0f);
      unsigned int K1 = (unsigned int)(int)ceilf(xv.y * 8388608.0f);
      unsigned int K2 = (unsigned int)(int)ceilf(xv.z * 8388608.0f);
      unsigned int K3 = (unsigned int)(int)ceilf(xv.w * 8388608.0f);
      unsigned int w4 = 0u;
      if ((tf_bits(base + 4 * q + 0) >> 9) < K0) w4 |= 1u;
      if ((tf_bits(base + 4 * q + 1) >> 9) < K1) w4 |= 1u << 8;
      if ((tf_bits(base + 4 * q + 2) >> 9) < K2) w4 |= 1u << 16;
      if ((tf_bits(base + 4 * q + 3) >> 9) < K3) w4 |= 1u << 24;
      wds[q] = w4;
    }
  }
  i32x4 v;
  v.x = (int)wds[0]; v.y = (int)wds[1]; v.z = (int)wds[2]; v.w = (int)wds[3];
  A[(size_t)(((t * 32 + mt) * 26) + kc) * 64 + lane] = v;
}

// ---------------------------------------------------------------------------
// setup: one thread per WEIGHT element writes all 5 digits; spikegen for ALL
// 50 steps appended (10,000 blocks). Block 0 also zeroes the lockstep bar.
// B1 layout: [nt:32][kc:26][s:5][lane:64][jj:16]  (per-nt span contiguous).
// B2 layout: [s:5][nt:4][kc:32][lane:64][jj:16].
// ---------------------------------------------------------------------------
__global__ __launch_bounds__(256) void setup_kernel(
    const float* __restrict__ W1, const float* __restrict__ W2,
    signed char* __restrict__ B1, signed char* __restrict__ B2,
    const float* __restrict__ x, i32x4* __restrict__ A,
    unsigned int* __restrict__ bar) {
  if (blockIdx.x >= PREP_BLOCKS) {
    spike_block(x, A, 0, blockIdx.x - PREP_BLOCKS, threadIdx.x);
    return;
  }
  if (blockIdx.x == 0 && threadIdx.x < 128) bar[threadIdx.x] = 0u;
  int idx = blockIdx.x * 256 + threadIdx.x;
  const int NB1 = 32 * 26 * 64 * 16;          // 851,968
  float w;
  signed char* dst;
  size_t stride;
  if (idx < NB1) {
    int jj = idx & 15;
    int lane = (idx >> 4) & 63;
    int kc = (idx >> 10) % 26;
    int nt = (idx >> 10) / 26;                // 0..31
    int k = kc * 32 + ((lane >> 5) << 4) + jj;
    int o = nt * 32 + (lane & 31);
    w = (o < 1000 && k < 784) ? W1[o * 784 + k] : 0.0f;
    dst = B1 + (size_t)(nt * 26 + kc) * 5120 + (lane << 4) + jj;
    stride = 1024;                            // s-stride within [kc] span
  } else {
    int m2 = idx - NB1;                       // < 131,072 (grid exact)
    int jj = m2 & 15;
    int lane = (m2 >> 4) & 63;
    int kc = (m2 >> 10) & 31;
    int nt = (m2 >> 10) >> 5;                 // 0..3
    int k = kc * 32 + ((lane >> 5) << 4) + jj;
    int o = nt * 32 + (lane & 31);
    w = (o < 100 && k < 1000) ? W2[o * 1000 + k] : 0.0f;
    dst = B2 + (size_t)(nt * 32 + kc) * 1024 + (lane << 4) + jj;
    stride = 4 * 32 * 1024;                   // s-stride (old layout)
  }
  long long V = llrint((double)w * 281474976710656.0);   // w * 2^48, exact
  signed char d = (signed char)(V & 0xFF);
  V = (V - (long long)d) >> 8;                // drop digit 0 (err <= 2^-41)
#pragma unroll
  for (int s = 0; s < 5; ++s) {
    d = (signed char)(V & 0xFF);
    V = (V - (long long)d) >> 8;
    dst[(size_t)s * stride] = d;
  }
}

// ---------------------------------------------------------------------------
// fused1: GEMM1 + layer-1 recurrence, all 50 steps in one dispatch.
// 256 blocks (id = nt*8 + mtg, XCD = id%8 = mtg) x 4 waves; wave owns tile
// (mt = mtg*4+wv, nt). B slices 0..2 pinned in 76,800 B LDS (ring-2 reads);
// slices 3,4 stream from global (ring-4, L2-resident per XCD). Single acc
// bank CA[5]; per-step epilogue: exact f64 Horner (integer < 2^47 => exact
// == int64 path). A: global ring-8. Every SYNC_EVERY steps the 32 blocks of
// group (id&7) lockstep via a capped atomic barrier (perf hint only).
// ---------------------------------------------------------------------------
#define F1_EPI_R(r) do {                                                      \
    double td = (double)CA[4][r];                                             \
    td = td * 256.0 + (double)CA[3][r];                                       \
    td = td * 256.0 + (double)CA[2][r];                                       \
    td = td * 256.0 + (double)CA[1][r];                                       \
    td = td * 256.0 + (double)CA[0][r];                                       \
    double I = td * 0x1p-40;                                                  \
    double mm = (((spk >> (r)) & 1u) ? 0.0 : m[r] * alpha) + I;               \
    m[r] = mm;                                                                \
    unsigned int sp = ((mm - 1.0) >= 0.0) ? 1u : 0u;                          \
    spk = (spk & ~(1u << (r))) | (sp << (r));                                 \
    hp[(size_t)(((r) & 3) + 8 * ((r) >> 2) + rb) * 1024] = (signed char)sp;   \
  } while (0)

__global__ __launch_bounds__(256, 1) void fused1_kernel(
    const signed char* __restrict__ B1, const i32x4* __restrict__ Afc,
    signed char* __restrict__ h1sc, const float* __restrict__ tau0,
    unsigned int* __restrict__ bar) {
  extern __shared__ i32x4 blsv[];             // [25 kc][3 sl][64] = 76,800 B
  const int tid = threadIdx.x, lane = tid & 63, wv = tid >> 6;
  const int id = (int)blockIdx.x;
  const int mtg = id & 7, nt = id >> 3;       // XCD = id%8 = mtg (A-locality)
  const int mt = mtg * 4 + wv;
  const i32x4* B1v = (const i32x4*)B1;

  // one-time B pin: digit slices 0..2 of this nt -> LDS (4800 i32x4)
  for (int r = tid; r < 4800; r += 256) {
    int kc = r / 192;
    int rem = r - kc * 192;                   // s*64 + lane
    blsv[r] = B1v[(size_t)nt * 8320 + (size_t)kc * 320 + rem];
  }

  const double alpha = 1.0 / (1.0 + exp(-(double)tau0[0]));
  double m[16];
  unsigned int spk = 0;
#pragma unroll
  for (int r = 0; r < 16; ++r) m[r] = 0.5;

  i32x16 Z;                                   // hoisted zero C-in for kc==0
#pragma unroll
  for (int i = 0; i < 16; ++i) Z[i] = 0;
  i32x16 CA[5];

  const i32x4* At = Afc + (size_t)mt * 26 * 64 + lane;   // t-stride 53,248
  const i32x4* Bg = B1v + (size_t)nt * 8320 + lane;      // slice-3/4 stream
  const int rb = 4 * (lane >> 5);
  signed char* hp = h1sc + (size_t)(mt * 32) * 1024 + nt * 32 + (lane & 31);

  // prologue global rings (independent of LDS, issue pre-barrier)
  i32x4 aR[8];
#pragma unroll
  for (int i = 0; i < 8; ++i) aR[i] = At[i * 64];
  i32x4 g3[4], g4[4];
#pragma unroll
  for (int i = 0; i < 4; ++i) {
    g3[i] = Bg[(i * 5 + 3) * 64];
    g4[i] = Bg[(i * 5 + 4) * 64];
  }

  __syncthreads();                            // LDS pin complete

  // prologue LDS ring (kc 0, 1; slices 0..2)
  i32x4 bR[2][3];
#pragma unroll
  for (int s = 0; s < 3; ++s) {
    bR[0][s] = blsv[(0 * 3 + s) * 64 + lane];
    bR[1][s] = blsv[(1 * 3 + s) * 64 + lane];
  }

#pragma unroll 1
  for (int t = 0; t < NSTEPS; ++t) {
#pragma unroll
    for (int kc = 0; kc < 25; ++kc) {
      i32x4 av = aR[kc & 7];
      if (kc + 8 < 25) aR[kc & 7] = At[(kc + 8) * 64];
      i32x4 q0 = bR[kc & 1][0], q1 = bR[kc & 1][1], q2 = bR[kc & 1][2];
      i32x4 q3 = g3[kc & 3], q4 = g4[kc & 3];
      if (kc + 2 < 25) {
#pragma unroll
        for (int s = 0; s < 3; ++s)
          bR[kc & 1][s] = blsv[((kc + 2) * 3 + s) * 64 + lane];
      }
      if (kc + 4 < 25) {
        g3[kc & 3] = Bg[((kc + 4) * 5 + 3) * 64];
        g4[kc & 3] = Bg[((kc + 4) * 5 + 4) * 64];
      }
      if (kc == 0) {
        CA[0] = __builtin_amdgcn_mfma_i32_32x32x32_i8(av, q0, Z, 0, 0, 0);
        CA[1] = __builtin_amdgcn_mfma_i32_32x32x32_i8(av, q1, Z, 0, 0, 0);
        CA[2] = __builtin_amdgcn_mfma_i32_32x32x32_i8(av, q2, Z, 0, 0, 0);
        CA[3] = __builtin_amdgcn_mfma_i32_32x32x32_i8(av, q3, Z, 0, 0, 0);
        CA[4] = __builtin_amdgcn_mfma_i32_32x32x32_i8(av, q4, Z, 0, 0, 0);
      } else {
        CA[0] = __builtin_amdgcn_mfma_i32_32x32x32_i8(av, q0, CA[0], 0, 0, 0);
        CA[1] = __builtin_amdgcn_mfma_i32_32x32x32_i8(av, q1, CA[1], 0, 0, 0);
        CA[2] = __builtin_amdgcn_mfma_i32_32x32x32_i8(av, q2, CA[2], 0, 0, 0);
        CA[3] = __builtin_amdgcn_mfma_i32_32x32x32_i8(av, q3, CA[3], 0, 0, 0);
        CA[4] = __builtin_amdgcn_mfma_i32_32x32x32_i8(av, q4, CA[4], 0, 0, 0);
      }
    }
    // next-step ring refills: issued BEFORE the epilogue so ~900cyc of f64
    // work hides global/LDS latency
    if (t + 1 < NSTEPS) At += 53248;
#pragma unroll
    for (int i = 0; i < 8; ++i) aR[i] = At[i * 64];
#pragma unroll
    for (int i = 0; i < 4; ++i) {
      g3[i] = Bg[(i * 5 + 3) * 64];
      g4[i] = Bg[(i * 5 + 4) * 64];
    }
#pragma unroll
    for (int s = 0; s < 3; ++s) {
      bR[0][s] = blsv[(0 * 3 + s) * 64 + lane];
      bR[1][s] = blsv[(1 * 3 + s) * 64 + lane];
    }
    // per-step epilogue: exact f64 Horner + pPLIF update + spike byte
#pragma unroll
    for (int r = 0; r < 16; ++r) F1_EPI_R(r);
    hp += 1048576;
    // lockstep: keep the 32 blocks sharing this A stream (group id&7)
    // within one interval so the stream stays L2-resident. Capped spin:
    // pure performance hint, never a correctness dependency.
    if (((t + 1) % SYNC_EVERY) == 0 && (t + 1) < NSTEPS) {
      __syncthreads();
      if (tid == 0) {
        int ph = (t + 1) / SYNC_EVERY - 1;    // 0..8
        unsigned int* c = bar + (mtg << 4) + ph;
        __hip_atomic_fetch_add(c, 1u, __ATOMIC_RELAXED,
                               __HIP_MEMORY_SCOPE_AGENT);
        for (int spin = 0; spin < 20000; ++spin) {
          if (__hip_atomic_load(c, __ATOMIC_RELAXED,
                                __HIP_MEMORY_SCOPE_AGENT) >= 32u) break;
          __builtin_amdgcn_s_sleep(2);
        }
      }
      __syncthreads();
    }
  }
}

// ---------------------------------------------------------------------------
// GEMM2: M=50*1024, N=128, K=1024, 5 slices. A = h1sc bytes row-major.
// LDS-staged B (wave w stages slice w, wave 0 also slice 4), double-buffered.
// ---------------------------------------------------------------------------
__global__ __launch_bounds__(256, 3) void gemm2_kernel(
    const signed char* __restrict__ Bf, const signed char* __restrict__ h1sc,
    double* __restrict__ T2) {
  __shared__ i32x4 bls[2][NSL][64];
  int tid = threadIdx.x, lane = tid & 63, wv = tid >> 6;
  int nt = blockIdx.x & 3;             // 0..3
  int mg = blockIdx.x >> 2;
  int tl = mg >> 3;                    // 0..49
  int mt = ((mg & 7) << 2) + wv;
  const signed char* Arow =
      h1sc + ((size_t)tl * 1024 + mt * 32 + (lane & 31)) * 1024 + ((lane >> 5) << 4);
  const i32x4* Bp = (const i32x4*)Bf + lane;
  const bool st4 = (wv == 0);
#define B2_IDX(s, kc) ((size_t)(((s) * 4 + nt) * 32 + (kc)) * 64)

  i32x16 C[NSL];
#pragma unroll
  for (int s = 0; s < NSL; ++s)
#pragma unroll
    for (int i = 0; i < 16; ++i) C[s][i] = 0;

  i32x4 sa = Bp[B2_IDX(wv, 0)];
  i32x4 sb; if (st4) sb = Bp[B2_IDX(4, 0)];
  i32x4 a0 = *(const i32x4*)(Arow);
  i32x4 a1 = *(const i32x4*)(Arow + 32);
  i32x4 a2;
  bls[0][wv][lane] = sa;
  if (st4) bls[0][4][lane] = sb;
  sa = Bp[B2_IDX(wv, 1)];
  if (st4) sb = Bp[B2_IDX(4, 1)];
  __syncthreads();

  for (int kc = 0; kc < 32; ++kc) {
    const int cur = kc & 1, nxt = cur ^ 1;
    if (kc + 1 < 32) {
      bls[nxt][wv][lane] = sa;
      if (st4) bls[nxt][4][lane] = sb;
    }
    if (kc + 2 < 32) {
      sa = Bp[B2_IDX(wv, kc + 2)];
      if (st4) sb = Bp[B2_IDX(4, kc + 2)];
      a2 = *(const i32x4*)(Arow + (size_t)(kc + 2) * 32);
    }
    i32x4 b0 = bls[cur][0][lane], b1 = bls[cur][1][lane], b2 = bls[cur][2][lane];
    i32x4 b3 = bls[cur][3][lane], b4 = bls[cur][4][lane];
    C[0] = __builtin_amdgcn_mfma_i32_32x32x32_i8(a0, b0, C[0], 0, 0, 0);
    C[1] = __builtin_amdgcn_mfma_i32_32x32x32_i8(a0, b1, C[1], 0, 0, 0);
    C[2] = __builtin_amdgcn_mfma_i32_32x32x32_i8(a0, b2, C[2], 0, 0, 0);
    C[3] = __builtin_amdgcn_mfma_i32_32x32x32_i8(a0, b3, C[3], 0, 0, 0);
    C[4] = __builtin_amdgcn_mfma_i32_32x32x32_i8(a0, b4, C[4], 0, 0, 0);
    a0 = a1; a1 = a2;
    __syncthreads();
  }

  int o = nt * 32 + (lane & 31);
  int rb = 4 * (lane >> 5);
#pragma unroll
  for (int r = 0; r < 16; ++r) {
    int row = (r & 3) + 8 * (r >> 2) + rb;
    int b = mt * 32 + row;
    long long T = (long long)C[4][r];
    T = (T << 8) + (long long)C[3][r];
    T = (T << 8) + (long long)C[2][r];
    T = (T << 8) + (long long)C[1][r];
    T = (T << 8) + (long long)C[0][r];
    T2[((size_t)tl * 1024 + b) * 128 + o] = (double)T * 0x1p-40;
  }
}

// ---------------------------------------------------------------------------
// rec2: layer-2 membrane recurrence + AvgPool(10) + pPLI accumulator.
// ---------------------------------------------------------------------------
__global__ __launch_bounds__(256) void rec2_kernel(
    const double* __restrict__ T2, double* __restrict__ h2m_st,
    signed char* __restrict__ h2s_st, double* __restrict__ acc_st,
    const float* __restrict__ tauv, const float* __restrict__ acct,
    int t0, int C, float* __restrict__ out) {
  __shared__ signed char sp[256];
  int tid = threadIdx.x;
  int b = blockIdx.x * 2 + (tid >> 7);
  int o = tid & 127;
  double alpha = 1.0 / (1.0 + exp(-(double)tauv[0]));
  double adec  = 1.0 / (1.0 + exp(-(double)acct[0]));
  double m, s, accv = 0.0;
  bool isPool = (o < 10);
  if (t0 == 0) {
    m = 0.5; s = 0.0;
  } else {
    m = h2m_st[(size_t)b * 128 + o];
    s = (double)h2s_st[(size_t)b * 128 + o];
    if (isPool) accv = acc_st[b * 10 + o];
  }
  for (int tl = 0; tl < C; ++tl) {
    double I = T2[((size_t)tl * 1024 + b) * 128 + o];
    m = (s != 0.0 ? 0.0 : m * alpha) + I;
    bool spk = (m - 1.0) >= 0.0;
    s = spk ? 1.0 : 0.0;
    sp[tid] = spk ? 1 : 0;
    __syncthreads();
    if (isPool) {
      int base = tid & 128;
      int isum = 0;
#pragma unroll
      for (int k = 0; k < 10; ++k) isum += sp[base + o * 10 + k];
      accv = accv * adec + (double)isum / 10.0;
      if (t0 + tl == NSTEPS - 1) out[b * 10 + o] = (float)accv;
    }
    __syncthreads();
  }
  h2m_st[(size_t)b * 128 + o] = m;
  h2s_st[(size_t)b * 128 + o] = (signed char)(s != 0.0 ? 1 : 0);
  if (isPool) acc_st[b * 10 + o] = accv;
}

// ---------------------------------------------------------------------------
extern "C" void kernel_launch(void* const* d_in, const int* in_sizes, int n_in,
                              void* d_out, int out_size, void* d_ws, size_t ws_size,
                              hipStream_t stream) {
  const float* x    = (const float*)d_in[0];
  const float* W1   = (const float*)d_in[1];
  const float* W2   = (const float*)d_in[2];
  const float* tau0 = (const float*)d_in[3];
  const float* tauv = (const float*)d_in[4];
  const float* acct = (const float*)d_in[5];
  float* out = (float*)d_out;
  char*  ws  = (char*)d_ws;

  signed char* B1     = (signed char*)(ws + OFF_B1);
  signed char* B2     = (signed char*)(ws + OFF_B2);
  signed char* Af     = (signed char*)(ws + OFF_AF);
  signed char* h1sc   = (signed char*)(ws + OFF_H1SC);
  double*      T2     = (double*)(ws + OFF_T2);
  double*      h2m_st = (double*)(ws + OFF_H2M);
  signed char* h2s_st = (signed char*)(ws + OFF_H2S);
  double*      acc_st = (double*)(ws + OFF_ACC);
  unsigned int* bar   = (unsigned int*)(ws + OFF_BAR);
  i32x4*       Afv    = (i32x4*)Af;

  // opt-in to 76,800 B dynamic LDS for fused1 (host-side, capture-safe)
  static bool attr_done = false;
  if (!attr_done) {
    (void)hipFuncSetAttribute((const void*)fused1_kernel,
                              hipFuncAttributeMaxDynamicSharedMemorySize,
                              76800);
    attr_done = true;
  }

  // 1) weight digit prep (3840 blocks) + spikegen for ALL 50 steps (10,000)
  setup_kernel<<<PREP_BLOCKS + NSTEPS * 200, 256, 0, stream>>>(
      W1, W2, B1, B2, x, Afv, bar);

  // 2) time-fused layer 1: all 50 steps, membranes register-resident
  fused1_kernel<<<256, 256, 76800, stream>>>(B1, Afv, h1sc, tau0, bar);

  // 3) layer 2 GEMM over all 50 steps
  gemm2_kernel<<<4 * NSTEPS * 8, 256, 0, stream>>>(B2, h1sc, T2);

  // 4) layer 2 recurrence + pooling + accumulator
  rec2_kernel<<<512, 256, 0, stream>>>(
      T2, h2m_st, h2s_st, acc_st, tauv, acct, 0, NSTEPS, out);
}

// Round 6
// 528.720 us; speedup vs baseline: 2.4541x; 1.1330x over previous
//
#include <hip/hip_runtime.h>
#include <hip/hip_bf16.h>
#include <math.h>

// ---------------------------------------------------------------------------
// sMLP4 round 15: TIME-FUSED layer 1 re-tiled to 16x16x64 / 2 m-tiles per
// wave / 8 waves per block.
// Round-14 post-mortem: traffic fixed (36 MB FETCH, 0 spill) but 401us at
// MfmaUtil 21.8%: per-CU per-kc the LDS pipe (144cyc), L2 (200cyc) and MFMA
// (182cyc) are ALL near budget and 1 wave/SIMD gives zero TLP to overlap
// their latencies -> 770cyc/kc, 65% dead. 32x32 tiles cap at 1 wave/SIMD
// (80 AGPR + f64 state ~212 regs). Re-tile:
//   - mfma_i32_16x16x64_i8: acc 4 regs/slice -> 2 m-tiles x 5 slices = 40
//     AGPR, m[8] f64 = 16 VGPR -> ~180 regs -> 2 waves/SIMD.
//   - 2 m-tiles share B frags: 5 ds_read_b128 feed 10 MFMAs. Per CU/step:
//     MFMA 5300cyc, LDS 5200cyc, L2 3500cyc -- balanced, TLP hides waits.
//   - B (13kc x 5sl, 65KB) pinned in LDS once; A global ring-2 per tile.
//   - grid 256 = nt*4 + mtg (64 nt x 4 mt-groups); XCD = id%8 pins mtg ->
//     per-XCD A window ~1MB per 5-step lockstep interval (L2-resident).
//     Lockstep: 4 groups x 64 blocks, capped spin (perf hint only).
// Exactness: C_s < 2^17, |T| < 2^49 < 2^53 -> f64 Horner exact; integer
// K-chunking associative -> trajectory bit-identical to rounds 10-14.
// ---------------------------------------------------------------------------

#define NSTEPS 50
#define KC1 13                     // K chunks of 64 for layer 1 (832 >= 784)
#define NSL 5                      // digit slices (digits 1..5 of 2^48 fix-pt)
#define SYNC_EVERY 5               // lockstep interval (steps)

typedef __attribute__((ext_vector_type(4)))  int i32x4;
typedef __attribute__((ext_vector_type(16))) int i32x16;

// fixed workspace layout (bytes, all 256-aligned)
#define OFF_B1     0ull            // i8 [64*13*5*64*16] = 4,259,840
#define OFF_B2     4259840ull      // i8 [5*4*32*1024]   =   655,360
#define OFF_AF     4915200ull      // i8 [50*64*13*64*16]= 42,598,400
#define OFF_H1SC   47513600ull     // i8 [50*1024*1024]  = 52,428,800
#define OFF_T2     99942400ull     // f64[50*1024*128]   = 52,428,800
#define OFF_H2M    152371200ull    // f64[1024*128]      = 1,048,576
#define OFF_H2S    153419776ull    // i8 [1024*128]      =   131,072
#define OFF_ACC    153550848ull    // f64[1024*10]       =    81,920
#define OFF_BAR    153632768ull    // u32[128] lockstep counters
#define WS_END     153633280ull    // 146.5 MB

#define PREP_BLOCKS 3840           // (851,968 + 131,072) / 256
#define SPK_BLOCKS 10400           // 50*64*13 waves / 4

// ---------------------------------------------------------------------------
// threefry2x32, key (0,42), partitionable mode: bits(i) = x0^x1 on ctr (0,i)
// ---------------------------------------------------------------------------
__device__ __forceinline__ unsigned int rotl32(unsigned int v, int d) {
#if __has_builtin(__builtin_amdgcn_alignbit)
  return __builtin_amdgcn_alignbit(v, v, (unsigned int)(32 - d));
#else
  return (v << d) | (v >> (32 - d));
#endif
}

__device__ __forceinline__ unsigned int tf_bits(unsigned int i) {
  const unsigned int ks0 = 0u;
  const unsigned int ks1 = 42u;
  const unsigned int ks2 = 0x1BD11BDAu ^ 0u ^ 42u;
  unsigned int x0 = 0u + ks0;
  unsigned int x1 = i + ks1;
#define TF_RND(r) { x0 += x1; x1 = rotl32(x1, r); x1 ^= x0; }
  TF_RND(13) TF_RND(15) TF_RND(26) TF_RND(6)
  x0 += ks1; x1 += ks2 + 1u;
  TF_RND(17) TF_RND(29) TF_RND(16) TF_RND(24)
  x0 += ks2; x1 += ks0 + 2u;
  TF_RND(13) TF_RND(15) TF_RND(26) TF_RND(6)
  x0 += ks0; x1 += ks1 + 3u;
  TF_RND(17) TF_RND(29) TF_RND(16) TF_RND(24)
  x0 += ks1; x1 += ks2 + 4u;
  TF_RND(13) TF_RND(15) TF_RND(26) TF_RND(6)
  x0 += ks2; x1 += ks0 + 5u;
#undef TF_RND
  return x0 ^ x1;
}

// ---------------------------------------------------------------------------
// spikegen role (one block = 4 waves = 4 (t,mt,kc) groups), 16x16x64 A-frag:
// lane holds A[b = mt*16+(lane&15)][k = kc*64+(lane>>4)*16+jj], jj 0..15.
// Integer compare: u < x  <=>  (bits>>9) < ceil(x*2^23)   (both exact).
// ---------------------------------------------------------------------------
__device__ __forceinline__ void spike_block(
    const float* __restrict__ x, i32x4* __restrict__ A, int gblk, int tid) {
  int g = gblk * 4 + (tid >> 6);
  int lane = tid & 63;
  int kc = g % 13;
  int r = g / 13;                     // t*64 + mt
  int mt = r & 63;
  int t = r >> 6;
  int b = mt * 16 + (lane & 15);
  int j0 = kc * 64 + ((lane >> 4) << 4);
  unsigned int wds[4] = {0u, 0u, 0u, 0u};
  if (j0 < 784) {                     // 784 = 49*16 (divergent only at kc=12)
    unsigned int base = (unsigned int)(t * 1024 + b) * 784u + (unsigned int)j0;
    const float* xp = x + b * 784 + j0;
#pragma unroll
    for (int q = 0; q < 4; ++q) {
      float4 xv = *(const float4*)(xp + 4 * q);
      unsigned int K0 = (unsigned int)(int)ceilf(xv.x * 8388608.0f);
      unsigned int K1 = (unsigned int)(int)ceilf(xv.y * 8388608.0f);
      unsigned int K2 = (unsigned int)(int)ceilf(xv.z * 8388608.0f);
      unsigned int K3 = (unsigned int)(int)ceilf(xv.w * 8388608.0f);
      unsigned int w4 = 0u;
      if ((tf_bits(base + 4 * q + 0) >> 9) < K0) w4 |= 1u;
      if ((tf_bits(base + 4 * q + 1) >> 9) < K1) w4 |= 1u << 8;
      if ((tf_bits(base + 4 * q + 2) >> 9) < K2) w4 |= 1u << 16;
      if ((tf_bits(base + 4 * q + 3) >> 9) < K3) w4 |= 1u << 24;
      wds[q] = w4;
    }
  }
  i32x4 v;
  v.x = (int)wds[0]; v.y = (int)wds[1]; v.z = (int)wds[2]; v.w = (int)wds[3];
  A[(size_t)((t * 64 + mt) * 13 + kc) * 64 + lane] = v;
}

// ---------------------------------------------------------------------------
// setup: one thread per WEIGHT element writes all 5 digits; spikegen for ALL
// 50 steps appended (10,400 blocks). Block 0 also zeroes the lockstep bar.
// B1 layout: [nt:64][kc:13][s:5][lane:64][jj:16]  (per-nt span contiguous).
// B-frag: lane holds B[k = kc*64+(lane>>4)*16+jj][o = nt*16+(lane&15)].
// B2 layout: [s:5][nt:4][kc:32][lane:64][jj:16] (unchanged, 32x32x32).
// ---------------------------------------------------------------------------
__global__ __launch_bounds__(256) void setup_kernel(
    const float* __restrict__ W1, const float* __restrict__ W2,
    signed char* __restrict__ B1, signed char* __restrict__ B2,
    const float* __restrict__ x, i32x4* __restrict__ A,
    unsigned int* __restrict__ bar) {
  if (blockIdx.x >= PREP_BLOCKS) {
    spike_block(x, A, blockIdx.x - PREP_BLOCKS, threadIdx.x);
    return;
  }
  if (blockIdx.x == 0 && threadIdx.x < 128) bar[threadIdx.x] = 0u;
  int idx = blockIdx.x * 256 + threadIdx.x;
  const int NB1 = 64 * 13 * 64 * 16;          // 851,968
  float w;
  signed char* dst;
  size_t stride;
  if (idx < NB1) {
    int jj = idx & 15;
    int lane = (idx >> 4) & 63;
    int kc = (idx >> 10) % 13;
    int nt = (idx >> 10) / 13;                // 0..63
    int k = kc * 64 + ((lane >> 4) << 4) + jj;
    int o = nt * 16 + (lane & 15);
    w = (o < 1000 && k < 784) ? W1[o * 784 + k] : 0.0f;
    dst = B1 + (size_t)(nt * 13 + kc) * 5120 + (lane << 4) + jj;
    stride = 1024;                            // s-stride within [kc] span
  } else {
    int m2 = idx - NB1;                       // < 131,072 (grid exact)
    int jj = m2 & 15;
    int lane = (m2 >> 4) & 63;
    int kc = (m2 >> 10) & 31;
    int nt = (m2 >> 10) >> 5;                 // 0..3
    int k = kc * 32 + ((lane >> 5) << 4) + jj;
    int o = nt * 32 + (lane & 31);
    w = (o < 100 && k < 1000) ? W2[o * 1000 + k] : 0.0f;
    dst = B2 + (size_t)(nt * 32 + kc) * 1024 + (lane << 4) + jj;
    stride = 4 * 32 * 1024;                   // s-stride (old layout)
  }
  long long V = llrint((double)w * 281474976710656.0);   // w * 2^48, exact
  signed char d = (signed char)(V & 0xFF);
  V = (V - (long long)d) >> 8;                // drop digit 0 (err <= 2^-41)
#pragma unroll
  for (int s = 0; s < 5; ++s) {
    d = (signed char)(V & 0xFF);
    V = (V - (long long)d) >> 8;
    dst[(size_t)s * stride] = d;
  }
}

// ---------------------------------------------------------------------------
// fused1: GEMM1 + layer-1 recurrence, all 50 steps in one dispatch.
// 256 blocks x 512 threads (8 waves). id = nt*4 + mtg: nt 0..63, mtg 0..3;
// XCD = id%8 = mtg + 4*(nt&1) -> each XCD serves ONE mtg (one A slice).
// Wave wv owns tiles (mtA, nt), (mtA+1, nt) with mtA = mtg*16 + wv*2
// (m-tile = 16 rows). B (13kc x 5sl of this nt) pinned in 65 KB LDS; the
// two m-tiles share B-frags: per kc 5 ds_read_b128 -> 10 MFMAs. A: global
// ring-2 per tile. Acc 40 AGPR. Epilogue per step: exact f64 Horner +
// pPLIF + spike byte. C/D 16x16: col = lane&15, row = (lane>>4)*4 + reg.
// ---------------------------------------------------------------------------
#define F1_EPI16(CP, mi, hpp, r) do {                                         \
    double td = (double)CP[4][r];                                             \
    td = td * 256.0 + (double)CP[3][r];                                       \
    td = td * 256.0 + (double)CP[2][r];                                       \
    td = td * 256.0 + (double)CP[1][r];                                       \
    td = td * 256.0 + (double)CP[0][r];                                       \
    double I = td * 0x1p-40;                                                  \
    double mm = (((spk >> (mi)) & 1u) ? 0.0 : m[mi] * alpha) + I;             \
    m[mi] = mm;                                                               \
    unsigned int sp = ((mm - 1.0) >= 0.0) ? 1u : 0u;                          \
    spk = (spk & ~(1u << (mi))) | (sp << (mi));                               \
    hpp[(r) * 1024] = (signed char)sp;                                        \
  } while (0)

__global__ __launch_bounds__(512, 1) void fused1_kernel(
    const signed char* __restrict__ B1, const i32x4* __restrict__ Afc,
    signed char* __restrict__ h1sc, const float* __restrict__ tau0,
    unsigned int* __restrict__ bar) {
  extern __shared__ i32x4 blsv[];             // [13 kc][5 sl][64] = 66,560 B
  const int tid = threadIdx.x, lane = tid & 63, wv = tid >> 6;  // wv 0..7
  const int id = (int)blockIdx.x;
  const int mtg = id & 3, nt = id >> 2;       // XCD pins mtg (A-locality)
  const int mtA = mtg * 16 + wv * 2;          // m-tiles mtA, mtA+1
  const i32x4* B1v = (const i32x4*)B1;

  // one-time B pin: all 13kc x 5sl of this nt -> LDS (4160 i32x4, contig)
  for (int r = tid; r < 4160; r += 512)
    blsv[r] = B1v[(size_t)nt * 4160 + r];

  const double alpha = 1.0 / (1.0 + exp(-(double)tau0[0]));
  double m[8];                                // rows: [0..3]=tileA, [4..7]=B
  unsigned int spk = 0;
#pragma unroll
  for (int r = 0; r < 8; ++r) m[r] = 0.5;

  i32x4 Z;                                    // hoisted zero C-in for kc==0
  Z.x = 0; Z.y = 0; Z.z = 0; Z.w = 0;
  i32x4 CA[5], CB[5];

  const i32x4* AtA = Afc + (size_t)(mtA * 13) * 64 + lane;     // t+=53,248
  const i32x4* AtB = AtA + 13 * 64;
  signed char* hpA = h1sc + (size_t)(mtA * 16 + ((lane >> 4) << 2)) * 1024
                   + nt * 16 + (lane & 15);
  signed char* hpB = hpA + 16 * 1024;

  // prologue A ring (t=0, kc 0,1) -- independent of LDS, issue pre-barrier
  i32x4 aA[2], aB[2];
  aA[0] = AtA[0]; aA[1] = AtA[64];
  aB[0] = AtB[0]; aB[1] = AtB[64];

  __syncthreads();                            // LDS pin complete

  // prologue B ring (kc 0,1; all 5 slices)
  i32x4 bR[2][5];
#pragma unroll
  for (int s = 0; s < 5; ++s) {
    bR[0][s] = blsv[(0 * 5 + s) * 64 + lane];
    bR[1][s] = blsv[(1 * 5 + s) * 64 + lane];
  }

#pragma unroll 1
  for (int t = 0; t < NSTEPS; ++t) {
#pragma unroll
    for (int kc = 0; kc < 13; ++kc) {
      i32x4 avA = aA[kc & 1], avB = aB[kc & 1];
      if (kc + 2 < 13) {
        aA[kc & 1] = AtA[(kc + 2) * 64];
        aB[kc & 1] = AtB[(kc + 2) * 64];
      }
      i32x4 q0 = bR[kc & 1][0], q1 = bR[kc & 1][1], q2 = bR[kc & 1][2],
            q3 = bR[kc & 1][3], q4 = bR[kc & 1][4];
      if (kc + 2 < 13) {
#pragma unroll
        for (int s = 0; s < 5; ++s)
          bR[kc & 1][s] = blsv[((kc + 2) * 5 + s) * 64 + lane];
      }
      if (kc == 0) {
        CA[0] = __builtin_amdgcn_mfma_i32_16x16x64_i8(avA, q0, Z, 0, 0, 0);
        CB[0] = __builtin_amdgcn_mfma_i32_16x16x64_i8(avB, q0, Z, 0, 0, 0);
        CA[1] = __builtin_amdgcn_mfma_i32_16x16x64_i8(avA, q1, Z, 0, 0, 0);
        CB[1] = __builtin_amdgcn_mfma_i32_16x16x64_i8(avB, q1, Z, 0, 0, 0);
        CA[2] = __builtin_amdgcn_mfma_i32_16x16x64_i8(avA, q2, Z, 0, 0, 0);
        CB[2] = __builtin_amdgcn_mfma_i32_16x16x64_i8(avB, q2, Z, 0, 0, 0);
        CA[3] = __builtin_amdgcn_mfma_i32_16x16x64_i8(avA, q3, Z, 0, 0, 0);
        CB[3] = __builtin_amdgcn_mfma_i32_16x16x64_i8(avB, q3, Z, 0, 0, 0);
        CA[4] = __builtin_amdgcn_mfma_i32_16x16x64_i8(avA, q4, Z, 0, 0, 0);
        CB[4] = __builtin_amdgcn_mfma_i32_16x16x64_i8(avB, q4, Z, 0, 0, 0);
      } else {
        CA[0] = __builtin_amdgcn_mfma_i32_16x16x64_i8(avA, q0, CA[0], 0, 0, 0);
        CB[0] = __builtin_amdgcn_mfma_i32_16x16x64_i8(avB, q0, CB[0], 0, 0, 0);
        CA[1] = __builtin_amdgcn_mfma_i32_16x16x64_i8(avA, q1, CA[1], 0, 0, 0);
        CB[1] = __builtin_amdgcn_mfma_i32_16x16x64_i8(avB, q1, CB[1], 0, 0, 0);
        CA[2] = __builtin_amdgcn_mfma_i32_16x16x64_i8(avA, q2, CA[2], 0, 0, 0);
        CB[2] = __builtin_amdgcn_mfma_i32_16x16x64_i8(avB, q2, CB[2], 0, 0, 0);
        CA[3] = __builtin_amdgcn_mfma_i32_16x16x64_i8(avA, q3, CA[3], 0, 0, 0);
        CB[3] = __builtin_amdgcn_mfma_i32_16x16x64_i8(avB, q3, CB[3], 0, 0, 0);
        CA[4] = __builtin_amdgcn_mfma_i32_16x16x64_i8(avA, q4, CA[4], 0, 0, 0);
        CB[4] = __builtin_amdgcn_mfma_i32_16x16x64_i8(avB, q4, CB[4], 0, 0, 0);
      }
    }
    // next-step ring refills: issued BEFORE the epilogue so the f64 work
    // hides global/LDS latency
    if (t + 1 < NSTEPS) { AtA += 53248; AtB += 53248; }
    aA[0] = AtA[0]; aA[1] = AtA[64];
    aB[0] = AtB[0]; aB[1] = AtB[64];
#pragma unroll
    for (int s = 0; s < 5; ++s) {
      bR[0][s] = blsv[(0 * 5 + s) * 64 + lane];
      bR[1][s] = blsv[(1 * 5 + s) * 64 + lane];
    }
    // per-step epilogue: exact f64 Horner + pPLIF update + spike bytes
#pragma unroll
    for (int r = 0; r < 4; ++r) F1_EPI16(CA, r, hpA, r);
#pragma unroll
    for (int r = 0; r < 4; ++r) F1_EPI16(CB, r + 4, hpB, r);
    hpA += 1048576; hpB += 1048576;
    // lockstep: keep the 64 blocks sharing this A stream (group id&3)
    // within one interval so the stream stays L2-resident. Capped spin:
    // pure performance hint, never a correctness dependency.
    if (((t + 1) % SYNC_EVERY) == 0 && (t + 1) < NSTEPS) {
      __syncthreads();
      if (tid == 0) {
        int ph = (t + 1) / SYNC_EVERY - 1;    // 0..8
        unsigned int* c = bar + (mtg << 4) + ph;
        __hip_atomic_fetch_add(c, 1u, __ATOMIC_RELAXED,
                               __HIP_MEMORY_SCOPE_AGENT);
        for (int spin = 0; spin < 20000; ++spin) {
          if (__hip_atomic_load(c, __ATOMIC_RELAXED,
                                __HIP_MEMORY_SCOPE_AGENT) >= 64u) break;
          __builtin_amdgcn_s_sleep(2);
        }
      }
      __syncthreads();
    }
  }
}

// ---------------------------------------------------------------------------
// GEMM2: M=50*1024, N=128, K=1024, 5 slices (32x32x32). A = h1sc row-major.
// LDS-staged B (wave w stages slice w, wave 0 also slice 4), double-buffered.
// ---------------------------------------------------------------------------
__global__ __launch_bounds__(256, 3) void gemm2_kernel(
    const signed char* __restrict__ Bf, const signed char* __restrict__ h1sc,
    double* __restrict__ T2) {
  __shared__ i32x4 bls[2][NSL][64];
  int tid = threadIdx.x, lane = tid & 63, wv = tid >> 6;
  int nt = blockIdx.x & 3;             // 0..3
  int mg = blockIdx.x >> 2;
  int tl = mg >> 3;                    // 0..49
  int mt = ((mg & 7) << 2) + wv;
  const signed char* Arow =
      h1sc + ((size_t)tl * 1024 + mt * 32 + (lane & 31)) * 1024 + ((lane >> 5) << 4);
  const i32x4* Bp = (const i32x4*)Bf + lane;
  const bool st4 = (wv == 0);
#define B2_IDX(s, kc) ((size_t)(((s) * 4 + nt) * 32 + (kc)) * 64)

  i32x16 C[NSL];
#pragma unroll
  for (int s = 0; s < NSL; ++s)
#pragma unroll
    for (int i = 0; i < 16; ++i) C[s][i] = 0;

  i32x4 sa = Bp[B2_IDX(wv, 0)];
  i32x4 sb; if (st4) sb = Bp[B2_IDX(4, 0)];
  i32x4 a0 = *(const i32x4*)(Arow);
  i32x4 a1 = *(const i32x4*)(Arow + 32);
  i32x4 a2;
  bls[0][wv][lane] = sa;
  if (st4) bls[0][4][lane] = sb;
  sa = Bp[B2_IDX(wv, 1)];
  if (st4) sb = Bp[B2_IDX(4, 1)];
  __syncthreads();

  for (int kc = 0; kc < 32; ++kc) {
    const int cur = kc & 1, nxt = cur ^ 1;
    if (kc + 1 < 32) {
      bls[nxt][wv][lane] = sa;
      if (st4) bls[nxt][4][lane] = sb;
    }
    if (kc + 2 < 32) {
      sa = Bp[B2_IDX(wv, kc + 2)];
      if (st4) sb = Bp[B2_IDX(4, kc + 2)];
      a2 = *(const i32x4*)(Arow + (size_t)(kc + 2) * 32);
    }
    i32x4 b0 = bls[cur][0][lane], b1 = bls[cur][1][lane], b2 = bls[cur][2][lane];
    i32x4 b3 = bls[cur][3][lane], b4 = bls[cur][4][lane];
    C[0] = __builtin_amdgcn_mfma_i32_32x32x32_i8(a0, b0, C[0], 0, 0, 0);
    C[1] = __builtin_amdgcn_mfma_i32_32x32x32_i8(a0, b1, C[1], 0, 0, 0);
    C[2] = __builtin_amdgcn_mfma_i32_32x32x32_i8(a0, b2, C[2], 0, 0, 0);
    C[3] = __builtin_amdgcn_mfma_i32_32x32x32_i8(a0, b3, C[3], 0, 0, 0);
    C[4] = __builtin_amdgcn_mfma_i32_32x32x32_i8(a0, b4, C[4], 0, 0, 0);
    a0 = a1; a1 = a2;
    __syncthreads();
  }

  int o = nt * 32 + (lane & 31);
  int rb = 4 * (lane >> 5);
#pragma unroll
  for (int r = 0; r < 16; ++r) {
    int row = (r & 3) + 8 * (r >> 2) + rb;
    int b = mt * 32 + row;
    long long T = (long long)C[4][r];
    T = (T << 8) + (long long)C[3][r];
    T = (T << 8) + (long long)C[2][r];
    T = (T << 8) + (long long)C[1][r];
    T = (T << 8) + (long long)C[0][r];
    T2[((size_t)tl * 1024 + b) * 128 + o] = (double)T * 0x1p-40;
  }
}

// ---------------------------------------------------------------------------
// rec2: layer-2 membrane recurrence + AvgPool(10) + pPLI accumulator.
// ---------------------------------------------------------------------------
__global__ __launch_bounds__(256) void rec2_kernel(
    const double* __restrict__ T2, double* __restrict__ h2m_st,
    signed char* __restrict__ h2s_st, double* __restrict__ acc_st,
    const float* __restrict__ tauv, const float* __restrict__ acct,
    int t0, int C, float* __restrict__ out) {
  __shared__ signed char sp[256];
  int tid = threadIdx.x;
  int b = blockIdx.x * 2 + (tid >> 7);
  int o = tid & 127;
  double alpha = 1.0 / (1.0 + exp(-(double)tauv[0]));
  double adec  = 1.0 / (1.0 + exp(-(double)acct[0]));
  double m, s, accv = 0.0;
  bool isPool = (o < 10);
  if (t0 == 0) {
    m = 0.5; s = 0.0;
  } else {
    m = h2m_st[(size_t)b * 128 + o];
    s = (double)h2s_st[(size_t)b * 128 + o];
    if (isPool) accv = acc_st[b * 10 + o];
  }
  for (int tl = 0; tl < C; ++tl) {
    double I = T2[((size_t)tl * 1024 + b) * 128 + o];
    m = (s != 0.0 ? 0.0 : m * alpha) + I;
    bool spk = (m - 1.0) >= 0.0;
    s = spk ? 1.0 : 0.0;
    sp[tid] = spk ? 1 : 0;
    __syncthreads();
    if (isPool) {
      int base = tid & 128;
      int isum = 0;
#pragma unroll
      for (int k = 0; k < 10; ++k) isum += sp[base + o * 10 + k];
      accv = accv * adec + (double)isum / 10.0;
      if (t0 + tl == NSTEPS - 1) out[b * 10 + o] = (float)accv;
    }
    __syncthreads();
  }
  h2m_st[(size_t)b * 128 + o] = m;
  h2s_st[(size_t)b * 128 + o] = (signed char)(s != 0.0 ? 1 : 0);
  if (isPool) acc_st[b * 10 + o] = accv;
}

// ---------------------------------------------------------------------------
extern "C" void kernel_launch(void* const* d_in, const int* in_sizes, int n_in,
                              void* d_out, int out_size, void* d_ws, size_t ws_size,
                              hipStream_t stream) {
  const float* x    = (const float*)d_in[0];
  const float* W1   = (const float*)d_in[1];
  const float* W2   = (const float*)d_in[2];
  const float* tau0 = (const float*)d_in[3];
  const float* tauv = (const float*)d_in[4];
  const float* acct = (const float*)d_in[5];
  float* out = (float*)d_out;
  char*  ws  = (char*)d_ws;

  signed char* B1     = (signed char*)(ws + OFF_B1);
  signed char* B2     = (signed char*)(ws + OFF_B2);
  signed char* Af     = (signed char*)(ws + OFF_AF);
  signed char* h1sc   = (signed char*)(ws + OFF_H1SC);
  double*      T2     = (double*)(ws + OFF_T2);
  double*      h2m_st = (double*)(ws + OFF_H2M);
  signed char* h2s_st = (signed char*)(ws + OFF_H2S);
  double*      acc_st = (double*)(ws + OFF_ACC);
  unsigned int* bar   = (unsigned int*)(ws + OFF_BAR);
  i32x4*       Afv    = (i32x4*)Af;

  // opt-in to 66,560 B dynamic LDS for fused1 (host-side, capture-safe)
  static bool attr_done = false;
  if (!attr_done) {
    (void)hipFuncSetAttribute((const void*)fused1_kernel,
                              hipFuncAttributeMaxDynamicSharedMemorySize,
                              66560);
    attr_done = true;
  }

  // 1) weight digit prep (3840 blocks) + spikegen for ALL 50 steps (10,400)
  setup_kernel<<<PREP_BLOCKS + SPK_BLOCKS, 256, 0, stream>>>(
      W1, W2, B1, B2, x, Afv, bar);

  // 2) time-fused layer 1: all 50 steps, membranes register-resident
  fused1_kernel<<<256, 512, 66560, stream>>>(B1, Afv, h1sc, tau0, bar);

  // 3) layer 2 GEMM over all 50 steps
  gemm2_kernel<<<4 * NSTEPS * 8, 256, 0, stream>>>(B2, h1sc, T2);

  // 4) layer 2 recurrence + pooling + accumulator
  rec2_kernel<<<512, 256, 0, stream>>>(
      T2, h2m_st, h2s_st, acc_st, tauv, acct, 0, NSTEPS, out);
}

// Round 7
// 464.602 us; speedup vs baseline: 2.7927x; 1.1380x over previous
//
#include <hip/hip_runtime.h>
#include <hip/hip_bf16.h>
#include <math.h>

// ---------------------------------------------------------------------------
// sMLP4 round 16: TIME-FUSED layer 1 (16x16x64, 8 waves, 2 waves/SIMD) with
// register-pinned B slices + LDS ring-3 + full-line h1sc writes.
// Round-15 post-mortem: 318us, MfmaUtil 28%, occupancy 2 waves/SIMD OK, but
// LDS pipe = 40 b128/kc/CU = 480cyc/kc (130us pure LDS wall vs 28us MFMA),
// ring-2 slack (~100cyc) < LDS latency (~150cyc) -> stalls; WRITE doubled
// (102 MB) from 16B partial-line writes (4 blocks own one 64B line).
// Fixes:
//   (1) B slices 3,4 REGISTER-PINNED per wave (time-invariant, 104 VGPR,
//       loaded once) -> LDS 24 b128/kc/CU (288cyc);
//   (2) LDS ring-3 (slack ~300cyc > latency);
//   (3) h1sc re-layout [t][o16:64][b:1024][o_lo:16]: each wave writes one
//       contiguous 512B span/step (full 64B lines); gemm2 Arow re-indexed
//       (still 16B/lane coalesced).
// Exactness: unchanged arithmetic => trajectory bit-identical to r10-15.
// ---------------------------------------------------------------------------

#define NSTEPS 50
#define KC1 13                     // K chunks of 64 for layer 1 (832 >= 784)
#define NSL 5                      // digit slices (digits 1..5 of 2^48 fix-pt)
#define SYNC_EVERY 5               // lockstep interval (steps)

typedef __attribute__((ext_vector_type(4)))  int i32x4;
typedef __attribute__((ext_vector_type(16))) int i32x16;

// fixed workspace layout (bytes, all 256-aligned)
#define OFF_B1     0ull            // i8 [64*13*5*64*16] = 4,259,840
#define OFF_B2     4259840ull      // i8 [5*4*32*1024]   =   655,360
#define OFF_AF     4915200ull      // i8 [50*64*13*64*16]= 42,598,400
#define OFF_H1SC   47513600ull     // i8 [50*64*1024*16] = 52,428,800
#define OFF_T2     99942400ull     // f64[50*1024*128]   = 52,428,800
#define OFF_H2M    152371200ull    // f64[1024*128]      = 1,048,576
#define OFF_H2S    153419776ull    // i8 [1024*128]      =   131,072
#define OFF_ACC    153550848ull    // f64[1024*10]       =    81,920
#define OFF_BAR    153632768ull    // u32[128] lockstep counters
#define WS_END     153633280ull    // 146.5 MB

#define PREP_BLOCKS 3840           // (851,968 + 131,072) / 256
#define SPK_BLOCKS 10400           // 50*64*13 waves / 4

// ---------------------------------------------------------------------------
// threefry2x32, key (0,42), partitionable mode: bits(i) = x0^x1 on ctr (0,i)
// ---------------------------------------------------------------------------
__device__ __forceinline__ unsigned int rotl32(unsigned int v, int d) {
#if __has_builtin(__builtin_amdgcn_alignbit)
  return __builtin_amdgcn_alignbit(v, v, (unsigned int)(32 - d));
#else
  return (v << d) | (v >> (32 - d));
#endif
}

__device__ __forceinline__ unsigned int tf_bits(unsigned int i) {
  const unsigned int ks0 = 0u;
  const unsigned int ks1 = 42u;
  const unsigned int ks2 = 0x1BD11BDAu ^ 0u ^ 42u;
  unsigned int x0 = 0u + ks0;
  unsigned int x1 = i + ks1;
#define TF_RND(r) { x0 += x1; x1 = rotl32(x1, r); x1 ^= x0; }
  TF_RND(13) TF_RND(15) TF_RND(26) TF_RND(6)
  x0 += ks1; x1 += ks2 + 1u;
  TF_RND(17) TF_RND(29) TF_RND(16) TF_RND(24)
  x0 += ks2; x1 += ks0 + 2u;
  TF_RND(13) TF_RND(15) TF_RND(26) TF_RND(6)
  x0 += ks0; x1 += ks1 + 3u;
  TF_RND(17) TF_RND(29) TF_RND(16) TF_RND(24)
  x0 += ks1; x1 += ks2 + 4u;
  TF_RND(13) TF_RND(15) TF_RND(26) TF_RND(6)
  x0 += ks2; x1 += ks0 + 5u;
#undef TF_RND
  return x0 ^ x1;
}

// ---------------------------------------------------------------------------
// spikegen role (one block = 4 waves = 4 (t,mt,kc) groups), 16x16x64 A-frag:
// lane holds A[b = mt*16+(lane&15)][k = kc*64+(lane>>4)*16+jj], jj 0..15.
// Integer compare: u < x  <=>  (bits>>9) < ceil(x*2^23)   (both exact).
// ---------------------------------------------------------------------------
__device__ __forceinline__ void spike_block(
    const float* __restrict__ x, i32x4* __restrict__ A, int gblk, int tid) {
  int g = gblk * 4 + (tid >> 6);
  int lane = tid & 63;
  int kc = g % 13;
  int r = g / 13;                     // t*64 + mt
  int mt = r & 63;
  int t = r >> 6;
  int b = mt * 16 + (lane & 15);
  int j0 = kc * 64 + ((lane >> 4) << 4);
  unsigned int wds[4] = {0u, 0u, 0u, 0u};
  if (j0 < 784) {                     // 784 = 49*16 (divergent only at kc=12)
    unsigned int base = (unsigned int)(t * 1024 + b) * 784u + (unsigned int)j0;
    const float* xp = x + b * 784 + j0;
#pragma unroll
    for (int q = 0; q < 4; ++q) {
      float4 xv = *(const float4*)(xp + 4 * q);
      unsigned int K0 = (unsigned int)(int)ceilf(xv.x * 8388608.0f);
      unsigned int K1 = (unsigned int)(int)ceilf(xv.y * 8388608.0f);
      unsigned int K2 = (unsigned int)(int)ceilf(xv.z * 8388608.0f);
      unsigned int K3 = (unsigned int)(int)ceilf(xv.w * 8388608.0f);
      unsigned int w4 = 0u;
      if ((tf_bits(base + 4 * q + 0) >> 9) < K0) w4 |= 1u;
      if ((tf_bits(base + 4 * q + 1) >> 9) < K1) w4 |= 1u << 8;
      if ((tf_bits(base + 4 * q + 2) >> 9) < K2) w4 |= 1u << 16;
      if ((tf_bits(base + 4 * q + 3) >> 9) < K3) w4 |= 1u << 24;
      wds[q] = w4;
    }
  }
  i32x4 v;
  v.x = (int)wds[0]; v.y = (int)wds[1]; v.z = (int)wds[2]; v.w = (int)wds[3];
  A[(size_t)((t * 64 + mt) * 13 + kc) * 64 + lane] = v;
}

// ---------------------------------------------------------------------------
// setup: one thread per WEIGHT element writes all 5 digits; spikegen for ALL
// 50 steps appended (10,400 blocks). Block 0 also zeroes the lockstep bar.
// B1 layout: [nt:64][kc:13][s:5][lane:64][jj:16]  (per-nt span contiguous).
// B-frag: lane holds B[k = kc*64+(lane>>4)*16+jj][o = nt*16+(lane&15)].
// B2 layout: [s:5][nt:4][kc:32][lane:64][jj:16] (unchanged, 32x32x32).
// ---------------------------------------------------------------------------
__global__ __launch_bounds__(256) void setup_kernel(
    const float* __restrict__ W1, const float* __restrict__ W2,
    signed char* __restrict__ B1, signed char* __restrict__ B2,
    const float* __restrict__ x, i32x4* __restrict__ A,
    unsigned int* __restrict__ bar) {
  if (blockIdx.x >= PREP_BLOCKS) {
    spike_block(x, A, blockIdx.x - PREP_BLOCKS, threadIdx.x);
    return;
  }
  if (blockIdx.x == 0 && threadIdx.x < 128) bar[threadIdx.x] = 0u;
  int idx = blockIdx.x * 256 + threadIdx.x;
  const int NB1 = 64 * 13 * 64 * 16;          // 851,968
  float w;
  signed char* dst;
  size_t stride;
  if (idx < NB1) {
    int jj = idx & 15;
    int lane = (idx >> 4) & 63;
    int kc = (idx >> 10) % 13;
    int nt = (idx >> 10) / 13;                // 0..63
    int k = kc * 64 + ((lane >> 4) << 4) + jj;
    int o = nt * 16 + (lane & 15);
    w = (o < 1000 && k < 784) ? W1[o * 784 + k] : 0.0f;
    dst = B1 + (size_t)(nt * 13 + kc) * 5120 + (lane << 4) + jj;
    stride = 1024;                            // s-stride within [kc] span
  } else {
    int m2 = idx - NB1;                       // < 131,072 (grid exact)
    int jj = m2 & 15;
    int lane = (m2 >> 4) & 63;
    int kc = (m2 >> 10) & 31;
    int nt = (m2 >> 10) >> 5;                 // 0..3
    int k = kc * 32 + ((lane >> 5) << 4) + jj;
    int o = nt * 32 + (lane & 31);
    w = (o < 100 && k < 1000) ? W2[o * 1000 + k] : 0.0f;
    dst = B2 + (size_t)(nt * 32 + kc) * 1024 + (lane << 4) + jj;
    stride = 4 * 32 * 1024;                   // s-stride (old layout)
  }
  long long V = llrint((double)w * 281474976710656.0);   // w * 2^48, exact
  signed char d = (signed char)(V & 0xFF);
  V = (V - (long long)d) >> 8;                // drop digit 0 (err <= 2^-41)
#pragma unroll
  for (int s = 0; s < 5; ++s) {
    d = (signed char)(V & 0xFF);
    V = (V - (long long)d) >> 8;
    dst[(size_t)s * stride] = d;
  }
}

// ---------------------------------------------------------------------------
// fused1: GEMM1 + layer-1 recurrence, all 50 steps in one dispatch.
// 256 blocks x 512 threads (8 waves). id = nt*4 + mtg; wave wv owns tiles
// (mtA, nt),(mtA+1, nt), mtA = mtg*16 + wv*2. B slices 3,4 register-pinned
// (time-invariant, 104 VGPR, loaded once); slices 0..2 in 39,936 B LDS with
// ring-3 prefetch; A global ring-2. Acc 40 regs. Per-step epilogue: exact
// f64 Horner + pPLIF + spike bytes to h1sc[t][o16][b][o_lo] (one contiguous
// 512 B span per wave -> full-line writes). Lockstep every SYNC_EVERY steps
// among the 64 blocks sharing an A slice (capped spin, perf hint only).
// C/D 16x16: col = lane&15, row = (lane>>4)*4 + reg.
// ---------------------------------------------------------------------------
#define F1_EPI16(CP, mi, hpp, r) do {                                         \
    double td = (double)CP[4][r];                                             \
    td = td * 256.0 + (double)CP[3][r];                                       \
    td = td * 256.0 + (double)CP[2][r];                                       \
    td = td * 256.0 + (double)CP[1][r];                                       \
    td = td * 256.0 + (double)CP[0][r];                                       \
    double I = td * 0x1p-40;                                                  \
    double mm = (((spk >> (mi)) & 1u) ? 0.0 : m[mi] * alpha) + I;             \
    m[mi] = mm;                                                               \
    unsigned int sp = ((mm - 1.0) >= 0.0) ? 1u : 0u;                          \
    spk = (spk & ~(1u << (mi))) | (sp << (mi));                               \
    hpp[(r) * 16] = (signed char)sp;                                          \
  } while (0)

__global__ __launch_bounds__(512, 1) void fused1_kernel(
    const signed char* __restrict__ B1, const i32x4* __restrict__ Afc,
    signed char* __restrict__ h1sc, const float* __restrict__ tau0,
    unsigned int* __restrict__ bar) {
  extern __shared__ i32x4 blsv[];             // [13 kc][3 sl][64] = 39,936 B
  const int tid = threadIdx.x, lane = tid & 63, wv = tid >> 6;  // wv 0..7
  const int id = (int)blockIdx.x;
  const int mtg = id & 3, nt = id >> 2;       // XCD pins mtg (A-locality)
  const int mtA = mtg * 16 + wv * 2;          // m-tiles mtA, mtA+1
  const i32x4* B1v = (const i32x4*)B1;

  // one-time B pin (slices 0..2) -> LDS (2496 i32x4)
  for (int r = tid; r < 2496; r += 512) {
    int kc = r / 192;
    int rem = r - kc * 192;                   // s*64 + lane, s in 0..2
    blsv[r] = B1v[(size_t)nt * 4160 + (size_t)kc * 320 + rem];
  }

  // register-pinned B slices 3,4 (time-invariant): 26 x b128 = 104 VGPR
  i32x4 p3[13], p4[13];
#pragma unroll
  for (int kc = 0; kc < 13; ++kc) {
    p3[kc] = B1v[(size_t)nt * 4160 + (size_t)kc * 320 + 3 * 64 + lane];
    p4[kc] = B1v[(size_t)nt * 4160 + (size_t)kc * 320 + 4 * 64 + lane];
  }

  const double alpha = 1.0 / (1.0 + exp(-(double)tau0[0]));
  double m[8];                                // rows: [0..3]=tileA, [4..7]=B
  unsigned int spk = 0;
#pragma unroll
  for (int r = 0; r < 8; ++r) m[r] = 0.5;

  i32x4 Z;                                    // hoisted zero C-in for kc==0
  Z.x = 0; Z.y = 0; Z.z = 0; Z.w = 0;
  i32x4 CA[5], CB[5];

  const i32x4* AtA = Afc + (size_t)(mtA * 13) * 64 + lane;     // t+=53,248
  const i32x4* AtB = AtA + 13 * 64;
  // h1sc[t][o16=nt][b][o_lo]: wave writes rows b = mtA*16 + (lane>>4)*4 + r
  signed char* hpA = h1sc
      + ((size_t)(nt) * 1024 + mtA * 16 + ((lane >> 4) << 2)) * 16
      + (lane & 15);
  signed char* hpB = hpA + 16 * 16;           // +16 rows

  // prologue A ring (t=0, kc 0,1) -- independent of LDS, issue pre-barrier
  i32x4 aA[2], aB[2];
  aA[0] = AtA[0]; aA[1] = AtA[64];
  aB[0] = AtB[0]; aB[1] = AtB[64];

  __syncthreads();                            // LDS pin complete

  // prologue LDS ring (kc 0,1,2; slices 0..2)
  i32x4 bR[3][3];
#pragma unroll
  for (int kc = 0; kc < 3; ++kc)
#pragma unroll
    for (int s = 0; s < 3; ++s)
      bR[kc][s] = blsv[(kc * 3 + s) * 64 + lane];

#pragma unroll 1
  for (int t = 0; t < NSTEPS; ++t) {
#pragma unroll
    for (int kc = 0; kc < 13; ++kc) {
      i32x4 avA = aA[kc & 1], avB = aB[kc & 1];
      if (kc + 2 < 13) {
        aA[kc & 1] = AtA[(kc + 2) * 64];
        aB[kc & 1] = AtB[(kc + 2) * 64];
      }
      i32x4 q0 = bR[kc % 3][0], q1 = bR[kc % 3][1], q2 = bR[kc % 3][2];
      i32x4 q3 = p3[kc], q4 = p4[kc];
      if (kc + 3 < 13) {
#pragma unroll
        for (int s = 0; s < 3; ++s)
          bR[kc % 3][s] = blsv[((kc + 3) * 3 + s) * 64 + lane];
      }
      if (kc == 0) {
        CA[0] = __builtin_amdgcn_mfma_i32_16x16x64_i8(avA, q0, Z, 0, 0, 0);
        CB[0] = __builtin_amdgcn_mfma_i32_16x16x64_i8(avB, q0, Z, 0, 0, 0);
        CA[1] = __builtin_amdgcn_mfma_i32_16x16x64_i8(avA, q1, Z, 0, 0, 0);
        CB[1] = __builtin_amdgcn_mfma_i32_16x16x64_i8(avB, q1, Z, 0, 0, 0);
        CA[2] = __builtin_amdgcn_mfma_i32_16x16x64_i8(avA, q2, Z, 0, 0, 0);
        CB[2] = __builtin_amdgcn_mfma_i32_16x16x64_i8(avB, q2, Z, 0, 0, 0);
        CA[3] = __builtin_amdgcn_mfma_i32_16x16x64_i8(avA, q3, Z, 0, 0, 0);
        CB[3] = __builtin_amdgcn_mfma_i32_16x16x64_i8(avB, q3, Z, 0, 0, 0);
        CA[4] = __builtin_amdgcn_mfma_i32_16x16x64_i8(avA, q4, Z, 0, 0, 0);
        CB[4] = __builtin_amdgcn_mfma_i32_16x16x64_i8(avB, q4, Z, 0, 0, 0);
      } else {
        CA[0] = __builtin_amdgcn_mfma_i32_16x16x64_i8(avA, q0, CA[0], 0, 0, 0);
        CB[0] = __builtin_amdgcn_mfma_i32_16x16x64_i8(avB, q0, CB[0], 0, 0, 0);
        CA[1] = __builtin_amdgcn_mfma_i32_16x16x64_i8(avA, q1, CA[1], 0, 0, 0);
        CB[1] = __builtin_amdgcn_mfma_i32_16x16x64_i8(avB, q1, CB[1], 0, 0, 0);
        CA[2] = __builtin_amdgcn_mfma_i32_16x16x64_i8(avA, q2, CA[2], 0, 0, 0);
        CB[2] = __builtin_amdgcn_mfma_i32_16x16x64_i8(avB, q2, CB[2], 0, 0, 0);
        CA[3] = __builtin_amdgcn_mfma_i32_16x16x64_i8(avA, q3, CA[3], 0, 0, 0);
        CB[3] = __builtin_amdgcn_mfma_i32_16x16x64_i8(avB, q3, CB[3], 0, 0, 0);
        CA[4] = __builtin_amdgcn_mfma_i32_16x16x64_i8(avA, q4, CA[4], 0, 0, 0);
        CB[4] = __builtin_amdgcn_mfma_i32_16x16x64_i8(avB, q4, CB[4], 0, 0, 0);
      }
    }
    // next-step ring refills: issued BEFORE the epilogue so the f64 work
    // hides global/LDS latency
    if (t + 1 < NSTEPS) { AtA += 53248; AtB += 53248; }
    aA[0] = AtA[0]; aA[1] = AtA[64];
    aB[0] = AtB[0]; aB[1] = AtB[64];
#pragma unroll
    for (int kc = 0; kc < 3; ++kc)
#pragma unroll
      for (int s = 0; s < 3; ++s)
        bR[kc][s] = blsv[(kc * 3 + s) * 64 + lane];
    // per-step epilogue: exact f64 Horner + pPLIF update + spike bytes
#pragma unroll
    for (int r = 0; r < 4; ++r) F1_EPI16(CA, r, hpA, r);
#pragma unroll
    for (int r = 0; r < 4; ++r) F1_EPI16(CB, r + 4, hpB, r);
    hpA += 1048576; hpB += 1048576;
    // lockstep: keep the 64 blocks sharing this A stream (group id&3)
    // within one interval so the stream stays L2-resident. Capped spin:
    // pure performance hint, never a correctness dependency.
    if (((t + 1) % SYNC_EVERY) == 0 && (t + 1) < NSTEPS) {
      __syncthreads();
      if (tid == 0) {
        int ph = (t + 1) / SYNC_EVERY - 1;    // 0..8
        unsigned int* c = bar + (mtg << 4) + ph;
        __hip_atomic_fetch_add(c, 1u, __ATOMIC_RELAXED,
                               __HIP_MEMORY_SCOPE_AGENT);
        for (int spin = 0; spin < 20000; ++spin) {
          if (__hip_atomic_load(c, __ATOMIC_RELAXED,
                                __HIP_MEMORY_SCOPE_AGENT) >= 64u) break;
          __builtin_amdgcn_s_sleep(2);
        }
      }
      __syncthreads();
    }
  }
}

// ---------------------------------------------------------------------------
// GEMM2: M=50*1024, N=128, K=1024, 5 slices (32x32x32). A = h1sc in
// [t][o16][b][o_lo] layout: lane reads 16B at o16 = kc*2+(lane>>5),
// b = mt*32+(lane&31) -- contiguous per lane, coalesced across lanes.
// LDS-staged B (wave w stages slice w, wave 0 also slice 4), double-buffered.
// ---------------------------------------------------------------------------
__global__ __launch_bounds__(256, 3) void gemm2_kernel(
    const signed char* __restrict__ Bf, const signed char* __restrict__ h1sc,
    double* __restrict__ T2) {
  __shared__ i32x4 bls[2][NSL][64];
  int tid = threadIdx.x, lane = tid & 63, wv = tid >> 6;
  int nt = blockIdx.x & 3;             // 0..3
  int mg = blockIdx.x >> 2;
  int tl = mg >> 3;                    // 0..49
  int mt = ((mg & 7) << 2) + wv;
  const i32x4* Ar = (const i32x4*)h1sc
      + ((size_t)tl * 64 + (lane >> 5)) * 1024 + mt * 32 + (lane & 31);
  const i32x4* Bp = (const i32x4*)Bf + lane;
  const bool st4 = (wv == 0);
#define B2_IDX(s, kc) ((size_t)(((s) * 4 + nt) * 32 + (kc)) * 64)

  i32x16 C[NSL];
#pragma unroll
  for (int s = 0; s < NSL; ++s)
#pragma unroll
    for (int i = 0; i < 16; ++i) C[s][i] = 0;

  i32x4 sa = Bp[B2_IDX(wv, 0)];
  i32x4 sb; if (st4) sb = Bp[B2_IDX(4, 0)];
  i32x4 a0 = Ar[0];
  i32x4 a1 = Ar[2048];
  i32x4 a2;
  bls[0][wv][lane] = sa;
  if (st4) bls[0][4][lane] = sb;
  sa = Bp[B2_IDX(wv, 1)];
  if (st4) sb = Bp[B2_IDX(4, 1)];
  __syncthreads();

  for (int kc = 0; kc < 32; ++kc) {
    const int cur = kc & 1, nxt = cur ^ 1;
    if (kc + 1 < 32) {
      bls[nxt][wv][lane] = sa;
      if (st4) bls[nxt][4][lane] = sb;
    }
    if (kc + 2 < 32) {
      sa = Bp[B2_IDX(wv, kc + 2)];
      if (st4) sb = Bp[B2_IDX(4, kc + 2)];
      a2 = Ar[(size_t)(kc + 2) * 2048];
    }
    i32x4 b0 = bls[cur][0][lane], b1 = bls[cur][1][lane], b2 = bls[cur][2][lane];
    i32x4 b3 = bls[cur][3][lane], b4 = bls[cur][4][lane];
    C[0] = __builtin_amdgcn_mfma_i32_32x32x32_i8(a0, b0, C[0], 0, 0, 0);
    C[1] = __builtin_amdgcn_mfma_i32_32x32x32_i8(a0, b1, C[1], 0, 0, 0);
    C[2] = __builtin_amdgcn_mfma_i32_32x32x32_i8(a0, b2, C[2], 0, 0, 0);
    C[3] = __builtin_amdgcn_mfma_i32_32x32x32_i8(a0, b3, C[3], 0, 0, 0);
    C[4] = __builtin_amdgcn_mfma_i32_32x32x32_i8(a0, b4, C[4], 0, 0, 0);
    a0 = a1; a1 = a2;
    __syncthreads();
  }

  int o = nt * 32 + (lane & 31);
  int rb = 4 * (lane >> 5);
#pragma unroll
  for (int r = 0; r < 16; ++r) {
    int row = (r & 3) + 8 * (r >> 2) + rb;
    int b = mt * 32 + row;
    long long T = (long long)C[4][r];
    T = (T << 8) + (long long)C[3][r];
    T = (T << 8) + (long long)C[2][r];
    T = (T << 8) + (long long)C[1][r];
    T = (T << 8) + (long long)C[0][r];
    T2[((size_t)tl * 1024 + b) * 128 + o] = (double)T * 0x1p-40;
  }
}

// ---------------------------------------------------------------------------
// rec2: layer-2 membrane recurrence + AvgPool(10) + pPLI accumulator.
// ---------------------------------------------------------------------------
__global__ __launch_bounds__(256) void rec2_kernel(
    const double* __restrict__ T2, double* __restrict__ h2m_st,
    signed char* __restrict__ h2s_st, double* __restrict__ acc_st,
    const float* __restrict__ tauv, const float* __restrict__ acct,
    int t0, int C, float* __restrict__ out) {
  __shared__ signed char sp[256];
  int tid = threadIdx.x;
  int b = blockIdx.x * 2 + (tid >> 7);
  int o = tid & 127;
  double alpha = 1.0 / (1.0 + exp(-(double)tauv[0]));
  double adec  = 1.0 / (1.0 + exp(-(double)acct[0]));
  double m, s, accv = 0.0;
  bool isPool = (o < 10);
  if (t0 == 0) {
    m = 0.5; s = 0.0;
  } else {
    m = h2m_st[(size_t)b * 128 + o];
    s = (double)h2s_st[(size_t)b * 128 + o];
    if (isPool) accv = acc_st[b * 10 + o];
  }
  for (int tl = 0; tl < C; ++tl) {
    double I = T2[((size_t)tl * 1024 + b) * 128 + o];
    m = (s != 0.0 ? 0.0 : m * alpha) + I;
    bool spk = (m - 1.0) >= 0.0;
    s = spk ? 1.0 : 0.0;
    sp[tid] = spk ? 1 : 0;
    __syncthreads();
    if (isPool) {
      int base = tid & 128;
      int isum = 0;
#pragma unroll
      for (int k = 0; k < 10; ++k) isum += sp[base + o * 10 + k];
      accv = accv * adec + (double)isum / 10.0;
      if (t0 + tl == NSTEPS - 1) out[b * 10 + o] = (float)accv;
    }
    __syncthreads();
  }
  h2m_st[(size_t)b * 128 + o] = m;
  h2s_st[(size_t)b * 128 + o] = (signed char)(s != 0.0 ? 1 : 0);
  if (isPool) acc_st[b * 10 + o] = accv;
}

// ---------------------------------------------------------------------------
extern "C" void kernel_launch(void* const* d_in, const int* in_sizes, int n_in,
                              void* d_out, int out_size, void* d_ws, size_t ws_size,
                              hipStream_t stream) {
  const float* x    = (const float*)d_in[0];
  const float* W1   = (const float*)d_in[1];
  const float* W2   = (const float*)d_in[2];
  const float* tau0 = (const float*)d_in[3];
  const float* tauv = (const float*)d_in[4];
  const float* acct = (const float*)d_in[5];
  float* out = (float*)d_out;
  char*  ws  = (char*)d_ws;

  signed char* B1     = (signed char*)(ws + OFF_B1);
  signed char* B2     = (signed char*)(ws + OFF_B2);
  signed char* Af     = (signed char*)(ws + OFF_AF);
  signed char* h1sc   = (signed char*)(ws + OFF_H1SC);
  double*      T2     = (double*)(ws + OFF_T2);
  double*      h2m_st = (double*)(ws + OFF_H2M);
  signed char* h2s_st = (signed char*)(ws + OFF_H2S);
  double*      acc_st = (double*)(ws + OFF_ACC);
  unsigned int* bar   = (unsigned int*)(ws + OFF_BAR);
  i32x4*       Afv    = (i32x4*)Af;

  // dynamic LDS for fused1 (39,936 B; attribute kept for safety)
  static bool attr_done = false;
  if (!attr_done) {
    (void)hipFuncSetAttribute((const void*)fused1_kernel,
                              hipFuncAttributeMaxDynamicSharedMemorySize,
                              39936);
    attr_done = true;
  }

  // 1) weight digit prep (3840 blocks) + spikegen for ALL 50 steps (10,400)
  setup_kernel<<<PREP_BLOCKS + SPK_BLOCKS, 256, 0, stream>>>(
      W1, W2, B1, B2, x, Afv, bar);

  // 2) time-fused layer 1: all 50 steps, membranes register-resident
  fused1_kernel<<<256, 512, 39936, stream>>>(B1, Afv, h1sc, tau0, bar);

  // 3) layer 2 GEMM over all 50 steps
  gemm2_kernel<<<4 * NSTEPS * 8, 256, 0, stream>>>(B2, h1sc, T2);

  // 4) layer 2 recurrence + pooling + accumulator
  rec2_kernel<<<512, 256, 0, stream>>>(
      T2, h2m_st, h2s_st, acc_st, tauv, acct, 0, NSTEPS, out);
}